// Round 1
// 274.104 us; speedup vs baseline: 1.1744x; 1.1744x over previous
//
#include <hip/hip_runtime.h>
#include <hip/hip_fp16.h>
#include <float.h>

#define NSEG 4096
#define CAP 2048   // max edges/segment held in LDS (max segment count ~330)

typedef __attribute__((ext_vector_type(8))) _Float16 half8;
typedef __attribute__((ext_vector_type(4))) float f32x4;

// ---- segment boundaries: segs[b] = first edge index with batch >= b ----
__global__ void seg_bounds(const int* __restrict__ batch, int* __restrict__ segs, int E) {
  int b = blockIdx.x * blockDim.x + threadIdx.x;
  if (b > NSEG) return;
  int lo = 0, hi = E;
  while (lo < hi) { int mid = (lo + hi) >> 1; if (batch[mid] < b) lo = mid + 1; else hi = mid; }
  segs[b] = lo;
}

// ---- pack W_j / W_i into MFMA B-fragment order, split fp16 hi/lo ----
// Layout (halves): Wpk[which][kt*8+nt][h(0=hi,1=lo)][lane][r]
//   value = W[k][n], k = kt*32 + (lane>>4)*8 + r, n = nt*16 + (lane&15)
// Per (kt,nt) frag-pair = 1024 halves (hi 512 + lo 512). Per matrix 32 KB*2 = 64 KB.
__global__ __launch_bounds__(256) void pack_w(
    const float* __restrict__ Wj, const float* __restrict__ Wi,
    __half* __restrict__ Wpk) {
  int tid = blockIdx.x * blockDim.x + threadIdx.x;
  for (int idx = tid; idx < 2 * 4 * 8 * 64 * 8; idx += gridDim.x * blockDim.x) {
    int r     = idx & 7;
    int l     = (idx >> 3) & 63;
    int nt    = (idx >> 9) & 7;
    int kt    = (idx >> 12) & 3;
    int which = idx >> 14;
    const float* W = which ? Wi : Wj;
    int k = kt * 32 + (l >> 4) * 8 + r;
    int n = nt * 16 + (l & 15);
    float v = W[k * 128 + n];
    __half hi = __float2half(v);                         // RNE
    __half lo = __float2half(v - __half2float(hi));      // exact residual, then RNE
    size_t base = ((size_t)which * 32 + (size_t)(kt * 8 + nt)) * 1024;
    Wpk[base + l * 8 + r]       = hi;
    Wpk[base + 512 + l * 8 + r] = lo;
  }
}

// ---- projection GEMM on matrix cores: Y = fp16(X @ W (+bias for which==1)) ----
// Split-fp16 3-MFMA trick: X = Xh + Xl, W = Wh + Wl (fp16 each);
// acc += Xh*Wh + Xl*Wh + Xh*Wl  (fp32 accumulate) -> ~fp32 precision.
// Per wave: 32 rows (2 m-tiles of 16) x full N=128 (8 n-tiles), K=128 (4 k-steps).
// A straight global->reg (lines fully consumed), B fragments streamed from
// L2-resident packed W (16B/lane coalesced). No LDS. 192 MFMA per wave.
__global__ __launch_bounds__(256) void proj_mfma(
    const float* __restrict__ Xj, const float* __restrict__ Xi,
    const float* __restrict__ bias, const __half* __restrict__ Wpk,
    __half* __restrict__ Yj, __half* __restrict__ Yi, int nrows) {
  const int which = blockIdx.y;
  const float* X = which ? Xi : Xj;
  __half* Y = which ? Yi : Yj;
  const _Float16* Wb = (const _Float16*)Wpk + (size_t)which * 32768;

  const int tid  = threadIdx.x;
  const int wid  = tid >> 6;
  const int lane = tid & 63;
  const int lr   = lane & 15;   // A row within m-tile / output col within n-tile
  const int lg   = lane >> 4;   // k-chunk group (A/B), row-quad group (D)

  const long row0 = (long)blockIdx.x * 128 + wid * 32;   // wave's 32 rows

  long rA0 = row0 + lr;
  long rA1 = row0 + 16 + lr;
  const float* pA0 = X + (rA0 < nrows ? rA0 : 0) * 128 + lg * 8;  // clamp: safe read
  const float* pA1 = X + (rA1 < nrows ? rA1 : 0) * 128 + lg * 8;

  // stage all A (2 m-tiles x 4 k-steps x 8 floats/lane) - constant-indexed, SROAs to regs
  float4 av0[4][2], av1[4][2];
  #pragma unroll
  for (int kt = 0; kt < 4; ++kt) {
    av0[kt][0] = *(const float4*)(pA0 + kt * 32);
    av0[kt][1] = *(const float4*)(pA0 + kt * 32 + 4);
    av1[kt][0] = *(const float4*)(pA1 + kt * 32);
    av1[kt][1] = *(const float4*)(pA1 + kt * 32 + 4);
  }

  f32x4 acc[2][8] = {};

#define CVT1(dsth, dstl, idx, val)                                   \
  { float v_ = (val); _Float16 h_ = (_Float16)v_;                    \
    dsth[idx] = h_; dstl[idx] = (_Float16)(v_ - (float)h_); }
#define CVT8(dsth, dstl, v0, v1)                                     \
  CVT1(dsth, dstl, 0, (v0).x) CVT1(dsth, dstl, 1, (v0).y)            \
  CVT1(dsth, dstl, 2, (v0).z) CVT1(dsth, dstl, 3, (v0).w)            \
  CVT1(dsth, dstl, 4, (v1).x) CVT1(dsth, dstl, 5, (v1).y)            \
  CVT1(dsth, dstl, 6, (v1).z) CVT1(dsth, dstl, 7, (v1).w)

  #pragma unroll
  for (int kt = 0; kt < 4; ++kt) {
    half8 a0h, a0l, a1h, a1l;
    CVT8(a0h, a0l, av0[kt][0], av0[kt][1]);
    CVT8(a1h, a1l, av1[kt][0], av1[kt][1]);
    const _Float16* fk = Wb + kt * 8192;
    #pragma unroll
    for (int nt = 0; nt < 8; ++nt) {
      const _Float16* f = fk + nt * 1024 + lane * 8;
      half8 bh = *(const half8*)(f);
      half8 bl = *(const half8*)(f + 512);
      acc[0][nt] = __builtin_amdgcn_mfma_f32_16x16x32_f16(a0h, bh, acc[0][nt], 0, 0, 0);
      acc[1][nt] = __builtin_amdgcn_mfma_f32_16x16x32_f16(a1h, bh, acc[1][nt], 0, 0, 0);
      acc[0][nt] = __builtin_amdgcn_mfma_f32_16x16x32_f16(a0l, bh, acc[0][nt], 0, 0, 0);
      acc[1][nt] = __builtin_amdgcn_mfma_f32_16x16x32_f16(a1l, bh, acc[1][nt], 0, 0, 0);
      acc[0][nt] = __builtin_amdgcn_mfma_f32_16x16x32_f16(a0h, bl, acc[0][nt], 0, 0, 0);
      acc[1][nt] = __builtin_amdgcn_mfma_f32_16x16x32_f16(a1h, bl, acc[1][nt], 0, 0, 0);
    }
  }
#undef CVT8
#undef CVT1

  float bcol[8];
  #pragma unroll
  for (int nt = 0; nt < 8; ++nt) bcol[nt] = which ? bias[nt * 16 + lr] : 0.f;

  // D layout: col = nt*16 + (lane&15), row = mtile*16 + (lane>>4)*4 + r
  #pragma unroll
  for (int mt = 0; mt < 2; ++mt) {
    #pragma unroll
    for (int r = 0; r < 4; ++r) {
      long row = row0 + mt * 16 + lg * 4 + r;
      if (row < nrows) {
        __half* yr = Y + row * 128 + lr;
        #pragma unroll
        for (int nt = 0; nt < 8; ++nt)
          yr[nt * 16] = __float2half(acc[mt][nt][r] + bcol[nt]);
      }
    }
  }
}

// One block per segment. Phase 1: alpha per edge, half-wave per edge,
// 4-edge unroll -> 8 gathers in flight per slot. Rows are fp16 (256B each,
// uint2 per lane) -> half the gather bytes of the fp32 version. No atomics.
__global__ __launch_bounds__(256) void seg_softmax(
    const __half* __restrict__ xjp, const __half* __restrict__ xip,
    const int* __restrict__ ei, const int* __restrict__ segs,
    const float* __restrict__ mlpW, const float* __restrict__ prelu_w,
    const float* __restrict__ mlp_b, float* __restrict__ out, int E) {
  const int start = segs[blockIdx.x];
  const int end = segs[blockIdx.x + 1];
  const int cnt = end - start;
  if (cnt <= 0) return;

  __shared__ float aS[CAP];
  __shared__ float red[8];

  const int tid = threadIdx.x;
  const int lane = tid & 63;
  const int sl = lane & 31;          // lane within half-wave
  const int slot = tid >> 5;         // 8 half-wave edge slots per block
  const int wid = tid >> 6;

  const float4 w = *(const float4*)(mlpW + sl * 4);
  const float pw = prelu_w[0];
  const float mb = mlp_b[0];
  const bool useLds = (cnt <= CAP);

#define GATHER4(node, arr, f01, f23)                                       \
  {                                                                        \
    uint2 u = *(const uint2*)((arr) + (long)(node) * 128 + sl * 4);        \
    f01 = __half22float2(*(__half2*)&u.x);                                 \
    f23 = __half22float2(*(__half2*)&u.y);                                 \
  }

  // ---- phase 1: alpha (4 edges per slot iteration) ----
  for (int e = start + slot; e < end; e += 32) {
    int e2 = e + 8, e3 = e + 16, e4 = e + 24;
    bool v2 = (e2 < end), v3 = (e3 < end), v4 = (e4 < end);
    int s1 = ei[e],             d1 = ei[E + e];
    int s2 = v2 ? ei[e2] : s1,  d2 = v2 ? ei[E + e2] : d1;
    int s3 = v3 ? ei[e3] : s1,  d3 = v3 ? ei[E + e3] : d1;
    int s4 = v4 ? ei[e4] : s1,  d4 = v4 ? ei[E + e4] : d1;

    float2 a1lo, a1hi, b1lo, b1hi, a2lo, a2hi, b2lo, b2hi;
    float2 a3lo, a3hi, b3lo, b3hi, a4lo, a4hi, b4lo, b4hi;
    GATHER4(s1, xjp, a1lo, a1hi); GATHER4(d1, xip, b1lo, b1hi);
    GATHER4(s2, xjp, a2lo, a2hi); GATHER4(d2, xip, b2lo, b2hi);
    GATHER4(s3, xjp, a3lo, a3hi); GATHER4(d3, xip, b3lo, b3hi);
    GATHER4(s4, xjp, a4lo, a4hi); GATHER4(d4, xip, b4lo, b4hi);

    float p1, p2, p3, p4;
#define ALPHA(alo, ahi, blo, bhi, p)                                        \
    {                                                                       \
      float h0 = alo.x + blo.x, h1 = alo.y + blo.y;                         \
      float h2 = ahi.x + bhi.x, h3 = ahi.y + bhi.y;                         \
      h0 = h0 >= 0.f ? h0 : pw * h0; h1 = h1 >= 0.f ? h1 : pw * h1;         \
      h2 = h2 >= 0.f ? h2 : pw * h2; h3 = h3 >= 0.f ? h3 : pw * h3;         \
      p = h0 * w.x + h1 * w.y + h2 * w.z + h3 * w.w;                        \
    }
    ALPHA(a1lo, a1hi, b1lo, b1hi, p1);
    ALPHA(a2lo, a2hi, b2lo, b2hi, p2);
    ALPHA(a3lo, a3hi, b3lo, b3hi, p3);
    ALPHA(a4lo, a4hi, b4lo, b4hi, p4);
#undef ALPHA

    #pragma unroll
    for (int off = 1; off < 32; off <<= 1) {
      p1 += __shfl_xor(p1, off, 64);
      p2 += __shfl_xor(p2, off, 64);
      p3 += __shfl_xor(p3, off, 64);
      p4 += __shfl_xor(p4, off, 64);
    }
    if (sl == 0) {
      if (useLds) {
        aS[e - start] = p1 + mb;
        if (v2) aS[e2 - start] = p2 + mb;
        if (v3) aS[e3 - start] = p3 + mb;
        if (v4) aS[e4 - start] = p4 + mb;
      } else {
        out[e] = p1 + mb;
        if (v2) out[e2] = p2 + mb;
        if (v3) out[e3] = p3 + mb;
        if (v4) out[e4] = p4 + mb;
      }
    }
  }
#undef GATHER4
  __syncthreads();

  // ---- phase 2: block max ----
  float m = -FLT_MAX;
  if (useLds) { for (int i = tid; i < cnt; i += 256) m = fmaxf(m, aS[i]); }
  else        { for (int i = tid; i < cnt; i += 256) m = fmaxf(m, out[start + i]); }
  #pragma unroll
  for (int off = 1; off < 64; off <<= 1) m = fmaxf(m, __shfl_xor(m, off, 64));
  if (lane == 0) red[wid] = m;
  __syncthreads();
  m = fmaxf(fmaxf(red[0], red[1]), fmaxf(red[2], red[3]));

  // ---- phase 3: exp + block sum ----
  float s = 0.f;
  if (useLds) {
    for (int i = tid; i < cnt; i += 256) { float x = expf(aS[i] - m); aS[i] = x; s += x; }
  } else {
    for (int i = tid; i < cnt; i += 256) { float x = expf(out[start + i] - m); out[start + i] = x; s += x; }
  }
  #pragma unroll
  for (int off = 1; off < 64; off <<= 1) s += __shfl_xor(s, off, 64);
  if (lane == 0) red[4 + wid] = s;
  __syncthreads();
  s = (red[4] + red[5]) + (red[6] + red[7]);

  // ---- phase 4: normalize + write ----
  const float inv = 1.0f / (s + 1e-16f);
  if (useLds) { for (int i = tid; i < cnt; i += 256) out[start + i] = aS[i] * inv; }
  else        { for (int i = tid; i < cnt; i += 256) out[start + i] *= inv; }
}

extern "C" void kernel_launch(void* const* d_in, const int* in_sizes, int n_in,
                              void* d_out, int out_size, void* d_ws, size_t ws_size,
                              hipStream_t stream) {
  const float* x_j      = (const float*)d_in[0];
  const float* x_i      = (const float*)d_in[1];
  const int*   edge_idx = (const int*)d_in[2];
  const int*   batch    = (const int*)d_in[3];
  const float* w_j      = (const float*)d_in[4];
  const float* w_i      = (const float*)d_in[5];
  const float* bias     = (const float*)d_in[6];
  const float* prelu_w  = (const float*)d_in[7];
  const float* mlp_W    = (const float*)d_in[8];
  const float* mlp_b    = (const float*)d_in[9];
  const int nnodes = in_sizes[0] / 128;
  const int E = in_sizes[3];

  __half* Wpk = (__half*)d_ws;                    // 65536 halves = 128 KB
  __half* xjp = Wpk + 65536;
  __half* xip = xjp + (size_t)nnodes * 128;
  int* segs   = (int*)(xip + (size_t)nnodes * 128);

  hipLaunchKernelGGL(seg_bounds, dim3((NSEG + 1 + 255) / 256), dim3(256), 0, stream,
                     batch, segs, E);

  hipLaunchKernelGGL(pack_w, dim3(32), dim3(256), 0, stream, w_j, w_i, Wpk);

  int gblocks = (nnodes + 127) / 128;
  hipLaunchKernelGGL(proj_mfma, dim3(gblocks, 2), dim3(256), 0, stream,
                     x_j, x_i, bias, Wpk, xjp, xip, nnodes);

  hipLaunchKernelGGL(seg_softmax, dim3(NSEG), dim3(256), 0, stream,
                     xjp, xip, edge_idx, segs, mlp_W, prelu_w, mlp_b,
                     (float*)d_out, E);
}

// Round 2
// 255.888 us; speedup vs baseline: 1.2580x; 1.0712x over previous
//
#include <hip/hip_runtime.h>
#include <hip/hip_fp16.h>
#include <float.h>

#define NSEG 4096
#define CAP 2048   // max edges/segment held in LDS (max segment count ~330)

typedef __attribute__((ext_vector_type(8))) _Float16 half8;
typedef __attribute__((ext_vector_type(4))) float f32x4;

// ---- segment boundaries: segs[b] = first edge index with batch >= b ----
__global__ void seg_bounds(const int* __restrict__ batch, int* __restrict__ segs, int E) {
  int b = blockIdx.x * blockDim.x + threadIdx.x;
  if (b > NSEG) return;
  int lo = 0, hi = E;
  while (lo < hi) { int mid = (lo + hi) >> 1; if (batch[mid] < b) lo = mid + 1; else hi = mid; }
  segs[b] = lo;
}

// ---- pack W_j / W_i into MFMA fragment order, split fp16 hi/lo ----
// Layout (halves): Wpk[which][kt*8+nt][h(0=hi,1=lo)][lane][r]
//   value = W[k][n], k = kt*32 + (lane>>4)*8 + r, n = nt*16 + (lane&15)
// This mapping serves as BOTH the B-fragment layout (col=lane&15) and the
// A-fragment layout (row=lane&15) -> usable directly as the A operand (=W^T).
__global__ __launch_bounds__(256) void pack_w(
    const float* __restrict__ Wj, const float* __restrict__ Wi,
    __half* __restrict__ Wpk) {
  int tid = blockIdx.x * blockDim.x + threadIdx.x;
  for (int idx = tid; idx < 2 * 4 * 8 * 64 * 8; idx += gridDim.x * blockDim.x) {
    int r     = idx & 7;
    int l     = (idx >> 3) & 63;
    int nt    = (idx >> 9) & 7;
    int kt    = (idx >> 12) & 3;
    int which = idx >> 14;
    const float* W = which ? Wi : Wj;
    int k = kt * 32 + (l >> 4) * 8 + r;
    int n = nt * 16 + (l & 15);
    float v = W[k * 128 + n];
    __half hi = __float2half(v);                         // RNE
    __half lo = __float2half(v - __half2float(hi));      // exact residual, then RNE
    size_t base = ((size_t)which * 32 + (size_t)(kt * 8 + nt)) * 1024;
    Wpk[base + l * 8 + r]       = hi;
    Wpk[base + 512 + l * 8 + r] = lo;
  }
}

// ---- projection GEMM on matrix cores: Y = fp16(X @ W (+bias for which==1)) ----
// Split-fp16 3-MFMA: acc += Wh*Xh + Wh*Xl + Wl*Xh (fp32 accumulate).
// v2 structure (fix for R1's latency-bound 9% MfmaUtil / VGPR=76):
//  - packed W (64 KB hi+lo) staged ONCE per block into LDS; K-loop reads
//    B..A-fragments via batched ds_read_b128 (short latency, lgkmcnt-scheduled)
//  - X prefetched one kt ahead into registers (rides under MFMA cluster)
//  - OPERAND SWAP: A=W-fragment, B=X-rows -> D holds 4 consecutive output
//    cols per lane -> packed 8B stores (16 per wave vs 64 scalar halves)
//  - no per-kt barriers (LDS read-only after the single staging barrier)
__global__ __launch_bounds__(256) void proj_mfma(
    const float* __restrict__ Xj, const float* __restrict__ Xi,
    const float* __restrict__ bias, const __half* __restrict__ Wpk,
    __half* __restrict__ Yj, __half* __restrict__ Yi, int nrows) {
  const int which = blockIdx.y;
  const float* X = which ? Xi : Xj;
  __half* Y = which ? Yi : Yj;

  __shared__ _Float16 Wlds[32768];   // 64 KB: [kt*8+nt][hi/lo][512 halves]

  const int tid  = threadIdx.x;
  const int wid  = tid >> 6;
  const int lane = tid & 63;
  const int lr   = lane & 15;   // X row within m-tile (B-frag 16-dim, D col idx j)
  const int lg   = lane >> 4;   // k-chunk group; D reg-quad selects output cols

  // ---- stage packed W into LDS: 64 KB = 256 thr * 16 iters * 16 B ----
  {
    const float4* src = (const float4*)(Wpk + (size_t)which * 32768);
    float4* dst = (float4*)Wlds;
    #pragma unroll
    for (int it = 0; it < 16; ++it)
      dst[it * 256 + tid] = src[it * 256 + tid];
  }

  const long row0 = (long)blockIdx.x * 128 + wid * 32;   // wave's 32 rows
  long r0 = row0 + lr;
  long r1 = row0 + 16 + lr;
  const float* p0 = X + (r0 < nrows ? r0 : 0) * 128 + lg * 8;  // clamp: safe read
  const float* p1 = X + (r1 < nrows ? r1 : 0) * 128 + lg * 8;

  // prologue: X for kt=0 in flight while we wait on the staging barrier
  float4 xa0 = *(const float4*)(p0);
  float4 xb0 = *(const float4*)(p0 + 4);
  float4 xa1 = *(const float4*)(p1);
  float4 xb1 = *(const float4*)(p1 + 4);

  __syncthreads();

  f32x4 acc[2][8] = {};

#define CVT1(dsth, dstl, idx, val)                                   \
  { float v_ = (val); _Float16 h_ = (_Float16)v_;                    \
    dsth[idx] = h_; dstl[idx] = (_Float16)(v_ - (float)h_); }
#define CVT8(dsth, dstl, v0, v1)                                     \
  CVT1(dsth, dstl, 0, (v0).x) CVT1(dsth, dstl, 1, (v0).y)            \
  CVT1(dsth, dstl, 2, (v0).z) CVT1(dsth, dstl, 3, (v0).w)            \
  CVT1(dsth, dstl, 4, (v1).x) CVT1(dsth, dstl, 5, (v1).y)            \
  CVT1(dsth, dstl, 6, (v1).z) CVT1(dsth, dstl, 7, (v1).w)

#define MFMA(a, b, c) __builtin_amdgcn_mfma_f32_16x16x32_f16((a), (b), (c), 0, 0, 0)

#define KT_STEP(kt, PREFETCH)                                            \
  {                                                                      \
    half8 wh[8], wl[8];                                                  \
    _Pragma("unroll")                                                    \
    for (int nt = 0; nt < 8; ++nt) {                                     \
      const _Float16* f = Wlds + ((kt) * 8 + nt) * 1024 + lane * 8;      \
      wh[nt] = *(const half8*)(f);                                       \
      wl[nt] = *(const half8*)(f + 512);                                 \
    }                                                                    \
    half8 xh0, xl0, xh1, xl1;                                            \
    CVT8(xh0, xl0, xa0, xb0);                                            \
    CVT8(xh1, xl1, xa1, xb1);                                            \
    if (PREFETCH) {                                                      \
      xa0 = *(const float4*)(p0 + ((kt) + 1) * 32);                      \
      xb0 = *(const float4*)(p0 + ((kt) + 1) * 32 + 4);                  \
      xa1 = *(const float4*)(p1 + ((kt) + 1) * 32);                      \
      xb1 = *(const float4*)(p1 + ((kt) + 1) * 32 + 4);                  \
    }                                                                    \
    _Pragma("unroll")                                                    \
    for (int nt = 0; nt < 8; ++nt) {                                     \
      acc[0][nt] = MFMA(wh[nt], xh0, acc[0][nt]);                        \
      acc[1][nt] = MFMA(wh[nt], xh1, acc[1][nt]);                        \
      acc[0][nt] = MFMA(wh[nt], xl0, acc[0][nt]);                        \
      acc[1][nt] = MFMA(wh[nt], xl1, acc[1][nt]);                        \
      acc[0][nt] = MFMA(wl[nt], xh0, acc[0][nt]);                        \
      acc[1][nt] = MFMA(wl[nt], xh1, acc[1][nt]);                        \
    }                                                                    \
  }

  KT_STEP(0, 1)
  KT_STEP(1, 1)
  KT_STEP(2, 1)
  KT_STEP(3, 0)

#undef KT_STEP
#undef MFMA
#undef CVT8
#undef CVT1

  // ---- epilogue: D layout (swapped): lane -> row = mt*16 + lr,
  //      cols = nt*16 + lg*4 + (0..3) -> packed 8B stores ----
  #pragma unroll
  for (int mt = 0; mt < 2; ++mt) {
    long row = row0 + mt * 16 + lr;
    if (row < nrows) {
      __half* yr = Y + row * 128;
      #pragma unroll
      for (int nt = 0; nt < 8; ++nt) {
        float4 bv = make_float4(0.f, 0.f, 0.f, 0.f);
        if (which) bv = *(const float4*)(bias + nt * 16 + lg * 4);
        __half2 v01 = __floats2half2_rn(acc[mt][nt][0] + bv.x, acc[mt][nt][1] + bv.y);
        __half2 v23 = __floats2half2_rn(acc[mt][nt][2] + bv.z, acc[mt][nt][3] + bv.w);
        uint2 u;
        u.x = *(unsigned int*)&v01;
        u.y = *(unsigned int*)&v23;
        *(uint2*)(yr + nt * 16 + lg * 4) = u;
      }
    }
  }
}

// One block per segment. Phase 1: alpha per edge, half-wave per edge,
// 4-edge unroll -> 8 gathers in flight per slot. Rows are fp16 (256B each,
// uint2 per lane) -> half the gather bytes of the fp32 version. No atomics.
__global__ __launch_bounds__(256) void seg_softmax(
    const __half* __restrict__ xjp, const __half* __restrict__ xip,
    const int* __restrict__ ei, const int* __restrict__ segs,
    const float* __restrict__ mlpW, const float* __restrict__ prelu_w,
    const float* __restrict__ mlp_b, float* __restrict__ out, int E) {
  const int start = segs[blockIdx.x];
  const int end = segs[blockIdx.x + 1];
  const int cnt = end - start;
  if (cnt <= 0) return;

  __shared__ float aS[CAP];
  __shared__ float red[8];

  const int tid = threadIdx.x;
  const int lane = tid & 63;
  const int sl = lane & 31;          // lane within half-wave
  const int slot = tid >> 5;         // 8 half-wave edge slots per block
  const int wid = tid >> 6;

  const float4 w = *(const float4*)(mlpW + sl * 4);
  const float pw = prelu_w[0];
  const float mb = mlp_b[0];
  const bool useLds = (cnt <= CAP);

#define GATHER4(node, arr, f01, f23)                                       \
  {                                                                        \
    uint2 u = *(const uint2*)((arr) + (long)(node) * 128 + sl * 4);        \
    f01 = __half22float2(*(__half2*)&u.x);                                 \
    f23 = __half22float2(*(__half2*)&u.y);                                 \
  }

  // ---- phase 1: alpha (4 edges per slot iteration) ----
  for (int e = start + slot; e < end; e += 32) {
    int e2 = e + 8, e3 = e + 16, e4 = e + 24;
    bool v2 = (e2 < end), v3 = (e3 < end), v4 = (e4 < end);
    int s1 = ei[e],             d1 = ei[E + e];
    int s2 = v2 ? ei[e2] : s1,  d2 = v2 ? ei[E + e2] : d1;
    int s3 = v3 ? ei[e3] : s1,  d3 = v3 ? ei[E + e3] : d1;
    int s4 = v4 ? ei[e4] : s1,  d4 = v4 ? ei[E + e4] : d1;

    float2 a1lo, a1hi, b1lo, b1hi, a2lo, a2hi, b2lo, b2hi;
    float2 a3lo, a3hi, b3lo, b3hi, a4lo, a4hi, b4lo, b4hi;
    GATHER4(s1, xjp, a1lo, a1hi); GATHER4(d1, xip, b1lo, b1hi);
    GATHER4(s2, xjp, a2lo, a2hi); GATHER4(d2, xip, b2lo, b2hi);
    GATHER4(s3, xjp, a3lo, a3hi); GATHER4(d3, xip, b3lo, b3hi);
    GATHER4(s4, xjp, a4lo, a4hi); GATHER4(d4, xip, b4lo, b4hi);

    float p1, p2, p3, p4;
#define ALPHA(alo, ahi, blo, bhi, p)                                        \
    {                                                                       \
      float h0 = alo.x + blo.x, h1 = alo.y + blo.y;                         \
      float h2 = ahi.x + bhi.x, h3 = ahi.y + bhi.y;                         \
      h0 = h0 >= 0.f ? h0 : pw * h0; h1 = h1 >= 0.f ? h1 : pw * h1;         \
      h2 = h2 >= 0.f ? h2 : pw * h2; h3 = h3 >= 0.f ? h3 : pw * h3;         \
      p = h0 * w.x + h1 * w.y + h2 * w.z + h3 * w.w;                        \
    }
    ALPHA(a1lo, a1hi, b1lo, b1hi, p1);
    ALPHA(a2lo, a2hi, b2lo, b2hi, p2);
    ALPHA(a3lo, a3hi, b3lo, b3hi, p3);
    ALPHA(a4lo, a4hi, b4lo, b4hi, p4);
#undef ALPHA

    #pragma unroll
    for (int off = 1; off < 32; off <<= 1) {
      p1 += __shfl_xor(p1, off, 64);
      p2 += __shfl_xor(p2, off, 64);
      p3 += __shfl_xor(p3, off, 64);
      p4 += __shfl_xor(p4, off, 64);
    }
    if (sl == 0) {
      if (useLds) {
        aS[e - start] = p1 + mb;
        if (v2) aS[e2 - start] = p2 + mb;
        if (v3) aS[e3 - start] = p3 + mb;
        if (v4) aS[e4 - start] = p4 + mb;
      } else {
        out[e] = p1 + mb;
        if (v2) out[e2] = p2 + mb;
        if (v3) out[e3] = p3 + mb;
        if (v4) out[e4] = p4 + mb;
      }
    }
  }
#undef GATHER4
  __syncthreads();

  // ---- phase 2: block max ----
  float m = -FLT_MAX;
  if (useLds) { for (int i = tid; i < cnt; i += 256) m = fmaxf(m, aS[i]); }
  else        { for (int i = tid; i < cnt; i += 256) m = fmaxf(m, out[start + i]); }
  #pragma unroll
  for (int off = 1; off < 64; off <<= 1) m = fmaxf(m, __shfl_xor(m, off, 64));
  if (lane == 0) red[wid] = m;
  __syncthreads();
  m = fmaxf(fmaxf(red[0], red[1]), fmaxf(red[2], red[3]));

  // ---- phase 3: exp + block sum ----
  float s = 0.f;
  if (useLds) {
    for (int i = tid; i < cnt; i += 256) { float x = expf(aS[i] - m); aS[i] = x; s += x; }
  } else {
    for (int i = tid; i < cnt; i += 256) { float x = expf(out[start + i] - m); out[start + i] = x; s += x; }
  }
  #pragma unroll
  for (int off = 1; off < 64; off <<= 1) s += __shfl_xor(s, off, 64);
  if (lane == 0) red[4 + wid] = s;
  __syncthreads();
  s = (red[4] + red[5]) + (red[6] + red[7]);

  // ---- phase 4: normalize + write ----
  const float inv = 1.0f / (s + 1e-16f);
  if (useLds) { for (int i = tid; i < cnt; i += 256) out[start + i] = aS[i] * inv; }
  else        { for (int i = tid; i < cnt; i += 256) out[start + i] *= inv; }
}

extern "C" void kernel_launch(void* const* d_in, const int* in_sizes, int n_in,
                              void* d_out, int out_size, void* d_ws, size_t ws_size,
                              hipStream_t stream) {
  const float* x_j      = (const float*)d_in[0];
  const float* x_i      = (const float*)d_in[1];
  const int*   edge_idx = (const int*)d_in[2];
  const int*   batch    = (const int*)d_in[3];
  const float* w_j      = (const float*)d_in[4];
  const float* w_i      = (const float*)d_in[5];
  const float* bias     = (const float*)d_in[6];
  const float* prelu_w  = (const float*)d_in[7];
  const float* mlp_W    = (const float*)d_in[8];
  const float* mlp_b    = (const float*)d_in[9];
  const int nnodes = in_sizes[0] / 128;
  const int E = in_sizes[3];

  __half* Wpk = (__half*)d_ws;                    // 65536 halves = 128 KB
  __half* xjp = Wpk + 65536;
  __half* xip = xjp + (size_t)nnodes * 128;
  int* segs   = (int*)(xip + (size_t)nnodes * 128);

  hipLaunchKernelGGL(seg_bounds, dim3((NSEG + 1 + 255) / 256), dim3(256), 0, stream,
                     batch, segs, E);

  hipLaunchKernelGGL(pack_w, dim3(32), dim3(256), 0, stream, w_j, w_i, Wpk);

  int gblocks = (nnodes + 127) / 128;
  hipLaunchKernelGGL(proj_mfma, dim3(gblocks, 2), dim3(256), 0, stream,
                     x_j, x_i, bias, Wpk, xjp, xip, nnodes);

  hipLaunchKernelGGL(seg_softmax, dim3(NSEG), dim3(256), 0, stream,
                     xjp, xip, edge_idx, segs, mlp_W, prelu_w, mlp_b,
                     (float*)d_out, E);
}

// Round 4
// 255.592 us; speedup vs baseline: 1.2595x; 1.0012x over previous
//
#include <hip/hip_runtime.h>
#include <hip/hip_fp16.h>
#include <float.h>

#define NSEG 4096
#define CAP 2048   // max edges/segment held in LDS (max segment count ~330)

typedef __attribute__((ext_vector_type(8))) _Float16 half8;
typedef __attribute__((ext_vector_type(2))) _Float16 h2v;
typedef __attribute__((ext_vector_type(4))) float f32x4;

// ---- segment boundaries: segs[b] = first edge index with batch >= b ----
__global__ void seg_bounds(const int* __restrict__ batch, int* __restrict__ segs, int E) {
  int b = blockIdx.x * blockDim.x + threadIdx.x;
  if (b > NSEG) return;
  int lo = 0, hi = E;
  while (lo < hi) { int mid = (lo + hi) >> 1; if (batch[mid] < b) lo = mid + 1; else hi = mid; }
  segs[b] = lo;
}

// ---- pack W_j / W_i into MFMA fragment order, split fp16 hi/lo ----
// Layout (halves): Wpk[which][kt*8+nt][h(0=hi,1=lo)][lane][r]
//   value = W[k][n], k = kt*32 + (lane>>4)*8 + r, n = nt*16 + (lane&15)
__global__ __launch_bounds__(256) void pack_w(
    const float* __restrict__ Wj, const float* __restrict__ Wi,
    __half* __restrict__ Wpk) {
  int tid = blockIdx.x * blockDim.x + threadIdx.x;
  for (int idx = tid; idx < 2 * 4 * 8 * 64 * 8; idx += gridDim.x * blockDim.x) {
    int r     = idx & 7;
    int l     = (idx >> 3) & 63;
    int nt    = (idx >> 9) & 7;
    int kt    = (idx >> 12) & 3;
    int which = idx >> 14;
    const float* W = which ? Wi : Wj;
    int k = kt * 32 + (l >> 4) * 8 + r;
    int n = nt * 16 + (l & 15);
    float v = W[k * 128 + n];
    __half hi = __float2half(v);                         // RNE
    __half lo = __float2half(v - __half2float(hi));      // exact residual, then RNE
    size_t base = ((size_t)which * 32 + (size_t)(kt * 8 + nt)) * 1024;
    Wpk[base + l * 8 + r]       = hi;
    Wpk[base + 512 + l * 8 + r] = lo;
  }
}

// ---- projection GEMM on matrix cores (unchanged from R2: LDS-staged W,
// operand swap, X prefetch) ----
__global__ __launch_bounds__(256) void proj_mfma(
    const float* __restrict__ Xj, const float* __restrict__ Xi,
    const float* __restrict__ bias, const __half* __restrict__ Wpk,
    __half* __restrict__ Yj, __half* __restrict__ Yi, int nrows) {
  const int which = blockIdx.y;
  const float* X = which ? Xi : Xj;
  __half* Y = which ? Yi : Yj;

  __shared__ _Float16 Wlds[32768];   // 64 KB: [kt*8+nt][hi/lo][512 halves]

  const int tid  = threadIdx.x;
  const int wid  = tid >> 6;
  const int lane = tid & 63;
  const int lr   = lane & 15;
  const int lg   = lane >> 4;

  {
    const float4* src = (const float4*)(Wpk + (size_t)which * 32768);
    float4* dst = (float4*)Wlds;
    #pragma unroll
    for (int it = 0; it < 16; ++it)
      dst[it * 256 + tid] = src[it * 256 + tid];
  }

  const long row0 = (long)blockIdx.x * 128 + wid * 32;
  long r0 = row0 + lr;
  long r1 = row0 + 16 + lr;
  const float* p0 = X + (r0 < nrows ? r0 : 0) * 128 + lg * 8;
  const float* p1 = X + (r1 < nrows ? r1 : 0) * 128 + lg * 8;

  float4 xa0 = *(const float4*)(p0);
  float4 xb0 = *(const float4*)(p0 + 4);
  float4 xa1 = *(const float4*)(p1);
  float4 xb1 = *(const float4*)(p1 + 4);

  __syncthreads();

  f32x4 acc[2][8] = {};

#define CVT1(dsth, dstl, idx, val)                                   \
  { float v_ = (val); _Float16 h_ = (_Float16)v_;                    \
    dsth[idx] = h_; dstl[idx] = (_Float16)(v_ - (float)h_); }
#define CVT8(dsth, dstl, v0, v1)                                     \
  CVT1(dsth, dstl, 0, (v0).x) CVT1(dsth, dstl, 1, (v0).y)            \
  CVT1(dsth, dstl, 2, (v0).z) CVT1(dsth, dstl, 3, (v0).w)            \
  CVT1(dsth, dstl, 4, (v1).x) CVT1(dsth, dstl, 5, (v1).y)            \
  CVT1(dsth, dstl, 6, (v1).z) CVT1(dsth, dstl, 7, (v1).w)

#define MFMA(a, b, c) __builtin_amdgcn_mfma_f32_16x16x32_f16((a), (b), (c), 0, 0, 0)

#define KT_STEP(kt, PREFETCH)                                            \
  {                                                                      \
    half8 wh[8], wl[8];                                                  \
    _Pragma("unroll")                                                    \
    for (int nt = 0; nt < 8; ++nt) {                                     \
      const _Float16* f = Wlds + ((kt) * 8 + nt) * 1024 + lane * 8;      \
      wh[nt] = *(const half8*)(f);                                       \
      wl[nt] = *(const half8*)(f + 512);                                 \
    }                                                                    \
    half8 xh0, xl0, xh1, xl1;                                            \
    CVT8(xh0, xl0, xa0, xb0);                                            \
    CVT8(xh1, xl1, xa1, xb1);                                            \
    if (PREFETCH) {                                                      \
      xa0 = *(const float4*)(p0 + ((kt) + 1) * 32);                      \
      xb0 = *(const float4*)(p0 + ((kt) + 1) * 32 + 4);                  \
      xa1 = *(const float4*)(p1 + ((kt) + 1) * 32);                      \
      xb1 = *(const float4*)(p1 + ((kt) + 1) * 32 + 4);                  \
    }                                                                    \
    _Pragma("unroll")                                                    \
    for (int nt = 0; nt < 8; ++nt) {                                     \
      acc[0][nt] = MFMA(wh[nt], xh0, acc[0][nt]);                        \
      acc[1][nt] = MFMA(wh[nt], xh1, acc[1][nt]);                        \
      acc[0][nt] = MFMA(wh[nt], xl0, acc[0][nt]);                        \
      acc[1][nt] = MFMA(wh[nt], xl1, acc[1][nt]);                        \
      acc[0][nt] = MFMA(wl[nt], xh0, acc[0][nt]);                        \
      acc[1][nt] = MFMA(wl[nt], xh1, acc[1][nt]);                        \
    }                                                                    \
  }

  KT_STEP(0, 1)
  KT_STEP(1, 1)
  KT_STEP(2, 1)
  KT_STEP(3, 0)

#undef KT_STEP
#undef MFMA
#undef CVT8
#undef CVT1

  #pragma unroll
  for (int mt = 0; mt < 2; ++mt) {
    long row = row0 + mt * 16 + lr;
    if (row < nrows) {
      __half* yr = Y + row * 128;
      #pragma unroll
      for (int nt = 0; nt < 8; ++nt) {
        float4 bv = make_float4(0.f, 0.f, 0.f, 0.f);
        if (which) bv = *(const float4*)(bias + nt * 16 + lg * 4);
        __half2 v01 = __floats2half2_rn(acc[mt][nt][0] + bv.x, acc[mt][nt][1] + bv.y);
        __half2 v23 = __floats2half2_rn(acc[mt][nt][2] + bv.z, acc[mt][nt][3] + bv.w);
        uint2 u;
        u.x = *(unsigned int*)&v01;
        u.y = *(unsigned int*)&v23;
        *(uint2*)(yr + nt * 16 + lg * 4) = u;
      }
    }
  }
}

// One block per segment.
// v3 phase 1 (fix for 54% VALUBusy + only 40% HBM: issue-bound, not BW-bound):
//  - QUARTER-wave (16 lanes) per edge, dwordx4 gathers (16 B/lane, still a
//    full coalesced 256 B row per group) -> half the VMEM instrs + addr calc
//  - packed fp16 add + PReLU via _Float16 vectors + __builtin_elementwise_max/min
//    (v_pk_add_f16 / v_pk_max_f16 / v_pk_min_f16 / v_pk_fma_f16), single cvt
//    to fp32, fp32 fma dot vs fp32 mlpW slice -> ~2x fewer VALU ops/edge
//  - 4-step shfl reduce over 16 lanes = 1 shfl/edge (was 2.5)
// Bytes per edge unchanged (512 B gather). Phases 2-4 unchanged.
__global__ __launch_bounds__(256) void seg_softmax(
    const __half* __restrict__ xjp, const __half* __restrict__ xip,
    const int* __restrict__ ei, const int* __restrict__ segs,
    const float* __restrict__ mlpW, const float* __restrict__ prelu_w,
    const float* __restrict__ mlp_b, float* __restrict__ out, int E) {
  const int start = segs[blockIdx.x];
  const int end = segs[blockIdx.x + 1];
  const int cnt = end - start;
  if (cnt <= 0) return;

  __shared__ float aS[CAP];
  __shared__ float red[8];

  const int tid = threadIdx.x;
  const int lane = tid & 63;
  const int wid = tid >> 6;
  const int g   = tid >> 4;          // 16 quarter-wave groups per block
  const int ql  = tid & 15;          // lane within group: 8 features x fp16

  const float4 w0 = *(const float4*)(mlpW + ql * 8);
  const float4 w1 = *(const float4*)(mlpW + ql * 8 + 4);
  const float pw = prelu_w[0];
  const float mb = mlp_b[0];
  const bool useLds = (cnt <= CAP);

  const uint4* XJ = (const uint4*)xjp;   // one row = 16 uint4 (256 B)
  const uint4* XI = (const uint4*)xip;
  const h2v pwv = { (_Float16)pw, (_Float16)pw };
  const h2v zv  = { (_Float16)0.f, (_Float16)0.f };

  // ---- phase 1: alpha (4 consecutive edges per group per iteration) ----
  for (int e0 = start + g * 4; e0 < end; e0 += 64) {
    const int eB = e0 + 1, eC = e0 + 2, eD = e0 + 3;
    const bool vB = (eB < end), vC = (eC < end), vD = (eD < end);
    int sA = ei[e0],            dA = ei[E + e0];
    int sB = vB ? ei[eB] : sA,  dB = vB ? ei[E + eB] : dA;
    int sC = vC ? ei[eC] : sA,  dC = vC ? ei[E + eC] : dA;
    int sD = vD ? ei[eD] : sA,  dD = vD ? ei[E + eD] : dA;

    uint4 aA = XJ[(size_t)sA * 16 + ql], bA = XI[(size_t)dA * 16 + ql];
    uint4 aB = XJ[(size_t)sB * 16 + ql], bB = XI[(size_t)dB * 16 + ql];
    uint4 aC = XJ[(size_t)sC * 16 + ql], bC = XI[(size_t)dC * 16 + ql];
    uint4 aD = XJ[(size_t)sD * 16 + ql], bD = XI[(size_t)dD * 16 + ql];

    float pA, pB, pC, pD;
#define EALPHA(av, bv, p)                                                   \
    {                                                                       \
      h2v h0 = *(h2v*)&(av).x + *(h2v*)&(bv).x;                             \
      h2v h1 = *(h2v*)&(av).y + *(h2v*)&(bv).y;                             \
      h2v h2 = *(h2v*)&(av).z + *(h2v*)&(bv).z;                             \
      h2v h3 = *(h2v*)&(av).w + *(h2v*)&(bv).w;                             \
      h0 = __builtin_elementwise_max(h0, zv)                                \
         + pwv * __builtin_elementwise_min(h0, zv);                         \
      h1 = __builtin_elementwise_max(h1, zv)                                \
         + pwv * __builtin_elementwise_min(h1, zv);                         \
      h2 = __builtin_elementwise_max(h2, zv)                                \
         + pwv * __builtin_elementwise_min(h2, zv);                         \
      h3 = __builtin_elementwise_max(h3, zv)                                \
         + pwv * __builtin_elementwise_min(h3, zv);                         \
      p = (float)h0.x * w0.x;                                               \
      p = fmaf((float)h0.y, w0.y, p); p = fmaf((float)h1.x, w0.z, p);       \
      p = fmaf((float)h1.y, w0.w, p); p = fmaf((float)h2.x, w1.x, p);       \
      p = fmaf((float)h2.y, w1.y, p); p = fmaf((float)h3.x, w1.z, p);       \
      p = fmaf((float)h3.y, w1.w, p);                                       \
    }
    EALPHA(aA, bA, pA);
    EALPHA(aB, bB, pB);
    EALPHA(aC, bC, pC);
    EALPHA(aD, bD, pD);
#undef EALPHA

    #pragma unroll
    for (int off = 1; off < 16; off <<= 1) {
      pA += __shfl_xor(pA, off, 64);
      pB += __shfl_xor(pB, off, 64);
      pC += __shfl_xor(pC, off, 64);
      pD += __shfl_xor(pD, off, 64);
    }
    if (ql == 0) {
      if (useLds) {
        aS[e0 - start] = pA + mb;
        if (vB) aS[eB - start] = pB + mb;
        if (vC) aS[eC - start] = pC + mb;
        if (vD) aS[eD - start] = pD + mb;
      } else {
        out[e0] = pA + mb;
        if (vB) out[eB] = pB + mb;
        if (vC) out[eC] = pC + mb;
        if (vD) out[eD] = pD + mb;
      }
    }
  }
  __syncthreads();

  // ---- phase 2: block max ----
  float m = -FLT_MAX;
  if (useLds) { for (int i = tid; i < cnt; i += 256) m = fmaxf(m, aS[i]); }
  else        { for (int i = tid; i < cnt; i += 256) m = fmaxf(m, out[start + i]); }
  #pragma unroll
  for (int off = 1; off < 64; off <<= 1) m = fmaxf(m, __shfl_xor(m, off, 64));
  if (lane == 0) red[wid] = m;
  __syncthreads();
  m = fmaxf(fmaxf(red[0], red[1]), fmaxf(red[2], red[3]));

  // ---- phase 3: exp + block sum ----
  float s = 0.f;
  if (useLds) {
    for (int i = tid; i < cnt; i += 256) { float x = expf(aS[i] - m); aS[i] = x; s += x; }
  } else {
    for (int i = tid; i < cnt; i += 256) { float x = expf(out[start + i] - m); out[start + i] = x; s += x; }
  }
  #pragma unroll
  for (int off = 1; off < 64; off <<= 1) s += __shfl_xor(s, off, 64);
  if (lane == 0) red[4 + wid] = s;
  __syncthreads();
  s = (red[4] + red[5]) + (red[6] + red[7]);

  // ---- phase 4: normalize + write ----
  const float inv = 1.0f / (s + 1e-16f);
  if (useLds) { for (int i = tid; i < cnt; i += 256) out[start + i] = aS[i] * inv; }
  else        { for (int i = tid; i < cnt; i += 256) out[start + i] *= inv; }
}

extern "C" void kernel_launch(void* const* d_in, const int* in_sizes, int n_in,
                              void* d_out, int out_size, void* d_ws, size_t ws_size,
                              hipStream_t stream) {
  const float* x_j      = (const float*)d_in[0];
  const float* x_i      = (const float*)d_in[1];
  const int*   edge_idx = (const int*)d_in[2];
  const int*   batch    = (const int*)d_in[3];
  const float* w_j      = (const float*)d_in[4];
  const float* w_i      = (const float*)d_in[5];
  const float* bias     = (const float*)d_in[6];
  const float* prelu_w  = (const float*)d_in[7];
  const float* mlp_W    = (const float*)d_in[8];
  const float* mlp_b    = (const float*)d_in[9];
  const int nnodes = in_sizes[0] / 128;
  const int E = in_sizes[3];

  __half* Wpk = (__half*)d_ws;                    // 65536 halves = 128 KB
  __half* xjp = Wpk + 65536;
  __half* xip = xjp + (size_t)nnodes * 128;
  int* segs   = (int*)(xip + (size_t)nnodes * 128);

  hipLaunchKernelGGL(seg_bounds, dim3((NSEG + 1 + 255) / 256), dim3(256), 0, stream,
                     batch, segs, E);

  hipLaunchKernelGGL(pack_w, dim3(32), dim3(256), 0, stream, w_j, w_i, Wpk);

  int gblocks = (nnodes + 127) / 128;
  hipLaunchKernelGGL(proj_mfma, dim3(gblocks, 2), dim3(256), 0, stream,
                     x_j, x_i, bias, Wpk, xjp, xip, nnodes);

  hipLaunchKernelGGL(seg_softmax, dim3(NSEG), dim3(256), 0, stream,
                     xjp, xip, edge_idx, segs, mlp_W, prelu_w, mlp_b,
                     (float*)d_out, E);
}

// Round 6
// 252.695 us; speedup vs baseline: 1.2739x; 1.0115x over previous
//
#include <hip/hip_runtime.h>
#include <hip/hip_fp16.h>
#include <float.h>

#define NSEG 4096
#define CAP 2048   // max edges/segment held in LDS (max segment count ~330)

typedef __attribute__((ext_vector_type(8))) _Float16 half8;
typedef __attribute__((ext_vector_type(2))) _Float16 h2v;
typedef __attribute__((ext_vector_type(4))) float f32x4;

// ---- segment boundaries: segs[b] = first edge index with batch >= b ----
__global__ void seg_bounds(const int* __restrict__ batch, int* __restrict__ segs, int E) {
  int b = blockIdx.x * blockDim.x + threadIdx.x;
  if (b > NSEG) return;
  int lo = 0, hi = E;
  while (lo < hi) { int mid = (lo + hi) >> 1; if (batch[mid] < b) lo = mid + 1; else hi = mid; }
  segs[b] = lo;
}

// ---- pack W_j / W_i into MFMA fragment order, split fp16 hi/lo ----
// Layout (halves): Wpk[which][kt*8+nt][h(0=hi,1=lo)][lane][r]
//   value = W[k][n], k = kt*32 + (lane>>4)*8 + r, n = nt*16 + (lane&15)
// One kt-chunk (8 frag-pairs) = 8192 halves = 16 KB = 1024 float4, contiguous.
__global__ __launch_bounds__(256) void pack_w(
    const float* __restrict__ Wj, const float* __restrict__ Wi,
    __half* __restrict__ Wpk) {
  int tid = blockIdx.x * blockDim.x + threadIdx.x;
  for (int idx = tid; idx < 2 * 4 * 8 * 64 * 8; idx += gridDim.x * blockDim.x) {
    int r     = idx & 7;
    int l     = (idx >> 3) & 63;
    int nt    = (idx >> 9) & 7;
    int kt    = (idx >> 12) & 3;
    int which = idx >> 14;
    const float* W = which ? Wi : Wj;
    int k = kt * 32 + (l >> 4) * 8 + r;
    int n = nt * 16 + (l & 15);
    float v = W[k * 128 + n];
    __half hi = __float2half(v);                         // RNE
    __half lo = __float2half(v - __half2float(hi));      // exact residual, then RNE
    size_t base = ((size_t)which * 32 + (size_t)(kt * 8 + nt)) * 1024;
    Wpk[base + l * 8 + r]       = hi;
    Wpk[base + 512 + l * 8 + r] = lo;
  }
}

// ---- projection GEMM on matrix cores: Y = fp16(X @ W (+bias for which==1)) ----
// v3b (R5 bugfix: a 16 KB kt-chunk = 1024 float4 -> 4 float4/thread staging,
// prologue and steady-state both; R5 staged only half the chunk -> NaN):
//  - W staged in per-kt 16 KB chunks, DOUBLE-BUFFERED in 32 KB LDS
//    (stage kt+1 while computing kt) -> 4 blocks/CU = 16 waves = 50% occ
//  - wh/wl fragment ds_reads JIT inside the nt-loop
//  - X prefetch depth 1; numerics identical (split-fp16 3-MFMA)
__global__ __launch_bounds__(256) void proj_mfma(
    const float* __restrict__ Xj, const float* __restrict__ Xi,
    const float* __restrict__ bias, const __half* __restrict__ Wpk,
    __half* __restrict__ Yj, __half* __restrict__ Yi, int nrows) {
  const int which = blockIdx.y;
  const float* X = which ? Xi : Xj;
  __half* Y = which ? Yi : Yj;
  const _Float16* WpkB = (const _Float16*)Wpk + (size_t)which * 32768;

  __shared__ _Float16 Wlds[2][8192];   // 2 x 16 KB kt-chunks

  const int tid  = threadIdx.x;
  const int wid  = tid >> 6;
  const int lane = tid & 63;
  const int lr   = lane & 15;
  const int lg   = lane >> 4;

  const long row0 = (long)blockIdx.x * 128 + wid * 32;
  long r0 = row0 + lr;
  long r1 = row0 + 16 + lr;
  const float* p0 = X + (r0 < nrows ? r0 : 0) * 128 + lg * 8;
  const float* p1 = X + (r1 < nrows ? r1 : 0) * 128 + lg * 8;

  // ---- prologue: stage W chunk 0 (16 KB = 1024 float4) + X for kt=0 ----
  {
    const float4* s_ = (const float4*)(WpkB);
    float4* d_ = (float4*)Wlds[0];
    d_[tid]       = s_[tid];
    d_[256 + tid] = s_[256 + tid];
    d_[512 + tid] = s_[512 + tid];
    d_[768 + tid] = s_[768 + tid];
  }
  float4 xa0 = *(const float4*)(p0);
  float4 xb0 = *(const float4*)(p0 + 4);
  float4 xa1 = *(const float4*)(p1);
  float4 xb1 = *(const float4*)(p1 + 4);

  __syncthreads();

  f32x4 acc[2][8] = {};

#define CVT1(dsth, dstl, idx, val)                                   \
  { float v_ = (val); _Float16 h_ = (_Float16)v_;                    \
    dsth[idx] = h_; dstl[idx] = (_Float16)(v_ - (float)h_); }
#define CVT8(dsth, dstl, v0, v1)                                     \
  CVT1(dsth, dstl, 0, (v0).x) CVT1(dsth, dstl, 1, (v0).y)            \
  CVT1(dsth, dstl, 2, (v0).z) CVT1(dsth, dstl, 3, (v0).w)            \
  CVT1(dsth, dstl, 4, (v1).x) CVT1(dsth, dstl, 5, (v1).y)            \
  CVT1(dsth, dstl, 6, (v1).z) CVT1(dsth, dstl, 7, (v1).w)

#define MFMA(a, b, c) __builtin_amdgcn_mfma_f32_16x16x32_f16((a), (b), (c), 0, 0, 0)

#define KT_STEP(kt, LAST)                                                \
  {                                                                      \
    float4 sw0, sw1, sw2, sw3;                                           \
    if (!(LAST)) {                                                       \
      const float4* s_ = (const float4*)(WpkB + ((kt) + 1) * 8192);      \
      sw0 = s_[tid];                                                     \
      sw1 = s_[256 + tid];                                               \
      sw2 = s_[512 + tid];                                               \
      sw3 = s_[768 + tid];                                               \
    }                                                                    \
    half8 xh0, xl0, xh1, xl1;                                            \
    CVT8(xh0, xl0, xa0, xb0);                                            \
    CVT8(xh1, xl1, xa1, xb1);                                            \
    if (!(LAST)) {                                                       \
      xa0 = *(const float4*)(p0 + ((kt) + 1) * 32);                      \
      xb0 = *(const float4*)(p0 + ((kt) + 1) * 32 + 4);                  \
      xa1 = *(const float4*)(p1 + ((kt) + 1) * 32);                      \
      xb1 = *(const float4*)(p1 + ((kt) + 1) * 32 + 4);                  \
      float4* d_ = (float4*)Wlds[((kt) + 1) & 1];                        \
      d_[tid]       = sw0;                                               \
      d_[256 + tid] = sw1;                                               \
      d_[512 + tid] = sw2;                                               \
      d_[768 + tid] = sw3;                                               \
    }                                                                    \
    _Pragma("unroll")                                                    \
    for (int nt = 0; nt < 8; ++nt) {                                     \
      const _Float16* f = &Wlds[(kt) & 1][nt * 1024 + lane * 8];         \
      half8 wh = *(const half8*)(f);                                     \
      half8 wl = *(const half8*)(f + 512);                               \
      acc[0][nt] = MFMA(wh, xh0, acc[0][nt]);                            \
      acc[1][nt] = MFMA(wh, xh1, acc[1][nt]);                            \
      acc[0][nt] = MFMA(wh, xl0, acc[0][nt]);                            \
      acc[1][nt] = MFMA(wh, xl1, acc[1][nt]);                            \
      acc[0][nt] = MFMA(wl, xh0, acc[0][nt]);                            \
      acc[1][nt] = MFMA(wl, xh1, acc[1][nt]);                            \
    }                                                                    \
    if (!(LAST)) __syncthreads();                                        \
  }

  KT_STEP(0, 0)
  KT_STEP(1, 0)
  KT_STEP(2, 0)
  KT_STEP(3, 1)

#undef KT_STEP
#undef MFMA
#undef CVT8
#undef CVT1

  // ---- epilogue: D layout (swapped): lane -> row = mt*16 + lr,
  //      cols = nt*16 + lg*4 + (0..3) -> packed 8B stores ----
  #pragma unroll
  for (int mt = 0; mt < 2; ++mt) {
    long row = row0 + mt * 16 + lr;
    if (row < nrows) {
      __half* yr = Y + row * 128;
      #pragma unroll
      for (int nt = 0; nt < 8; ++nt) {
        float4 bv = make_float4(0.f, 0.f, 0.f, 0.f);
        if (which) bv = *(const float4*)(bias + nt * 16 + lg * 4);
        __half2 v01 = __floats2half2_rn(acc[mt][nt][0] + bv.x, acc[mt][nt][1] + bv.y);
        __half2 v23 = __floats2half2_rn(acc[mt][nt][2] + bv.z, acc[mt][nt][3] + bv.w);
        uint2 u;
        u.x = *(unsigned int*)&v01;
        u.y = *(unsigned int*)&v23;
        *(uint2*)(yr + nt * 16 + lg * 4) = u;
      }
    }
  }
}

// One block per segment. (unchanged from R4 — control: pinned at ~3.4 TB/s
// beyond-L2 across two structurally different versions -> L3 random-line
// bandwidth/concurrency wall; fp8 traffic cut fails the error budget)
__global__ __launch_bounds__(256) void seg_softmax(
    const __half* __restrict__ xjp, const __half* __restrict__ xip,
    const int* __restrict__ ei, const int* __restrict__ segs,
    const float* __restrict__ mlpW, const float* __restrict__ prelu_w,
    const float* __restrict__ mlp_b, float* __restrict__ out, int E) {
  const int start = segs[blockIdx.x];
  const int end = segs[blockIdx.x + 1];
  const int cnt = end - start;
  if (cnt <= 0) return;

  __shared__ float aS[CAP];
  __shared__ float red[8];

  const int tid = threadIdx.x;
  const int lane = tid & 63;
  const int wid = tid >> 6;
  const int g   = tid >> 4;          // 16 quarter-wave groups per block
  const int ql  = tid & 15;          // lane within group: 8 features x fp16

  const float4 w0 = *(const float4*)(mlpW + ql * 8);
  const float4 w1 = *(const float4*)(mlpW + ql * 8 + 4);
  const float pw = prelu_w[0];
  const float mb = mlp_b[0];
  const bool useLds = (cnt <= CAP);

  const uint4* XJ = (const uint4*)xjp;   // one row = 16 uint4 (256 B)
  const uint4* XI = (const uint4*)xip;
  const h2v pwv = { (_Float16)pw, (_Float16)pw };
  const h2v zv  = { (_Float16)0.f, (_Float16)0.f };

  // ---- phase 1: alpha (4 consecutive edges per group per iteration) ----
  for (int e0 = start + g * 4; e0 < end; e0 += 64) {
    const int eB = e0 + 1, eC = e0 + 2, eD = e0 + 3;
    const bool vB = (eB < end), vC = (eC < end), vD = (eD < end);
    int sA = ei[e0],            dA = ei[E + e0];
    int sB = vB ? ei[eB] : sA,  dB = vB ? ei[E + eB] : dA;
    int sC = vC ? ei[eC] : sA,  dC = vC ? ei[E + eC] : dA;
    int sD = vD ? ei[eD] : sA,  dD = vD ? ei[E + eD] : dA;

    uint4 aA = XJ[(size_t)sA * 16 + ql], bA = XI[(size_t)dA * 16 + ql];
    uint4 aB = XJ[(size_t)sB * 16 + ql], bB = XI[(size_t)dB * 16 + ql];
    uint4 aC = XJ[(size_t)sC * 16 + ql], bC = XI[(size_t)dC * 16 + ql];
    uint4 aD = XJ[(size_t)sD * 16 + ql], bD = XI[(size_t)dD * 16 + ql];

    float pA, pB, pC, pD;
#define EALPHA(av, bv, p)                                                   \
    {                                                                       \
      h2v h0 = *(h2v*)&(av).x + *(h2v*)&(bv).x;                             \
      h2v h1 = *(h2v*)&(av).y + *(h2v*)&(bv).y;                             \
      h2v h2 = *(h2v*)&(av).z + *(h2v*)&(bv).z;                             \
      h2v h3 = *(h2v*)&(av).w + *(h2v*)&(bv).w;                             \
      h0 = __builtin_elementwise_max(h0, zv)                                \
         + pwv * __builtin_elementwise_min(h0, zv);                         \
      h1 = __builtin_elementwise_max(h1, zv)                                \
         + pwv * __builtin_elementwise_min(h1, zv);                         \
      h2 = __builtin_elementwise_max(h2, zv)                                \
         + pwv * __builtin_elementwise_min(h2, zv);                         \
      h3 = __builtin_elementwise_max(h3, zv)                                \
         + pwv * __builtin_elementwise_min(h3, zv);                         \
      p = (float)h0.x * w0.x;                                               \
      p = fmaf((float)h0.y, w0.y, p); p = fmaf((float)h1.x, w0.z, p);       \
      p = fmaf((float)h1.y, w0.w, p); p = fmaf((float)h2.x, w1.x, p);       \
      p = fmaf((float)h2.y, w1.y, p); p = fmaf((float)h3.x, w1.z, p);       \
      p = fmaf((float)h3.y, w1.w, p);                                       \
    }
    EALPHA(aA, bA, pA);
    EALPHA(aB, bB, pB);
    EALPHA(aC, bC, pC);
    EALPHA(aD, bD, pD);
#undef EALPHA

    #pragma unroll
    for (int off = 1; off < 16; off <<= 1) {
      pA += __shfl_xor(pA, off, 64);
      pB += __shfl_xor(pB, off, 64);
      pC += __shfl_xor(pC, off, 64);
      pD += __shfl_xor(pD, off, 64);
    }
    if (ql == 0) {
      if (useLds) {
        aS[e0 - start] = pA + mb;
        if (vB) aS[eB - start] = pB + mb;
        if (vC) aS[eC - start] = pC + mb;
        if (vD) aS[eD - start] = pD + mb;
      } else {
        out[e0] = pA + mb;
        if (vB) out[eB] = pB + mb;
        if (vC) out[eC] = pC + mb;
        if (vD) out[eD] = pD + mb;
      }
    }
  }
  __syncthreads();

  // ---- phase 2: block max ----
  float m = -FLT_MAX;
  if (useLds) { for (int i = tid; i < cnt; i += 256) m = fmaxf(m, aS[i]); }
  else        { for (int i = tid; i < cnt; i += 256) m = fmaxf(m, out[start + i]); }
  #pragma unroll
  for (int off = 1; off < 64; off <<= 1) m = fmaxf(m, __shfl_xor(m, off, 64));
  if (lane == 0) red[wid] = m;
  __syncthreads();
  m = fmaxf(fmaxf(red[0], red[1]), fmaxf(red[2], red[3]));

  // ---- phase 3: exp + block sum ----
  float s = 0.f;
  if (useLds) {
    for (int i = tid; i < cnt; i += 256) { float x = expf(aS[i] - m); aS[i] = x; s += x; }
  } else {
    for (int i = tid; i < cnt; i += 256) { float x = expf(out[start + i] - m); out[start + i] = x; s += x; }
  }
  #pragma unroll
  for (int off = 1; off < 64; off <<= 1) s += __shfl_xor(s, off, 64);
  if (lane == 0) red[4 + wid] = s;
  __syncthreads();
  s = (red[4] + red[5]) + (red[6] + red[7]);

  // ---- phase 4: normalize + write ----
  const float inv = 1.0f / (s + 1e-16f);
  if (useLds) { for (int i = tid; i < cnt; i += 256) out[start + i] = aS[i] * inv; }
  else        { for (int i = tid; i < cnt; i += 256) out[start + i] *= inv; }
}

extern "C" void kernel_launch(void* const* d_in, const int* in_sizes, int n_in,
                              void* d_out, int out_size, void* d_ws, size_t ws_size,
                              hipStream_t stream) {
  const float* x_j      = (const float*)d_in[0];
  const float* x_i      = (const float*)d_in[1];
  const int*   edge_idx = (const int*)d_in[2];
  const int*   batch    = (const int*)d_in[3];
  const float* w_j      = (const float*)d_in[4];
  const float* w_i      = (const float*)d_in[5];
  const float* bias     = (const float*)d_in[6];
  const float* prelu_w  = (const float*)d_in[7];
  const float* mlp_W    = (const float*)d_in[8];
  const float* mlp_b    = (const float*)d_in[9];
  const int nnodes = in_sizes[0] / 128;
  const int E = in_sizes[3];

  __half* Wpk = (__half*)d_ws;                    // 65536 halves = 128 KB
  __half* xjp = Wpk + 65536;
  __half* xip = xjp + (size_t)nnodes * 128;
  int* segs   = (int*)(xip + (size_t)nnodes * 128);

  hipLaunchKernelGGL(seg_bounds, dim3((NSEG + 1 + 255) / 256), dim3(256), 0, stream,
                     batch, segs, E);

  hipLaunchKernelGGL(pack_w, dim3(32), dim3(256), 0, stream, w_j, w_i, Wpk);

  int gblocks = (nnodes + 127) / 128;
  hipLaunchKernelGGL(proj_mfma, dim3(gblocks, 2), dim3(256), 0, stream,
                     x_j, x_i, bias, Wpk, xjp, xip, nnodes);

  hipLaunchKernelGGL(seg_softmax, dim3(NSEG), dim3(256), 0, stream,
                     xjp, xip, edge_idx, segs, mlp_W, prelu_w, mlp_b,
                     (float*)d_out, E);
}

// Round 7
// 252.641 us; speedup vs baseline: 1.2742x; 1.0002x over previous
//
#include <hip/hip_runtime.h>
#include <hip/hip_fp16.h>
#include <float.h>

#define NSEG 4096
#define CAP 2048   // max edges/segment held in LDS (max segment count ~330)

typedef __attribute__((ext_vector_type(8))) _Float16 half8;
typedef __attribute__((ext_vector_type(2))) _Float16 h2v;
typedef __attribute__((ext_vector_type(4))) float f32x4;

// ---- segment boundaries: segs[b] = first edge index with batch >= b ----
__global__ void seg_bounds(const int* __restrict__ batch, int* __restrict__ segs, int E) {
  int b = blockIdx.x * blockDim.x + threadIdx.x;
  if (b > NSEG) return;
  int lo = 0, hi = E;
  while (lo < hi) { int mid = (lo + hi) >> 1; if (batch[mid] < b) lo = mid + 1; else hi = mid; }
  segs[b] = lo;
}

// ---- pack W_j / W_i into MFMA fragment order, split fp16 hi/lo ----
// Layout (halves): Wpk[which][kt*8+nt][h(0=hi,1=lo)][lane][r]
//   value = W[k][n], k = kt*32 + (lane>>4)*8 + r, n = nt*16 + (lane&15)
// One kt-chunk (8 frag-pairs) = 8192 halves = 16 KB = 1024 float4, contiguous.
__global__ __launch_bounds__(256) void pack_w(
    const float* __restrict__ Wj, const float* __restrict__ Wi,
    __half* __restrict__ Wpk) {
  int tid = blockIdx.x * blockDim.x + threadIdx.x;
  for (int idx = tid; idx < 2 * 4 * 8 * 64 * 8; idx += gridDim.x * blockDim.x) {
    int r     = idx & 7;
    int l     = (idx >> 3) & 63;
    int nt    = (idx >> 9) & 7;
    int kt    = (idx >> 12) & 3;
    int which = idx >> 14;
    const float* W = which ? Wi : Wj;
    int k = kt * 32 + (l >> 4) * 8 + r;
    int n = nt * 16 + (l & 15);
    float v = W[k * 128 + n];
    __half hi = __float2half(v);                         // RNE
    __half lo = __float2half(v - __half2float(hi));      // exact residual, then RNE
    size_t base = ((size_t)which * 32 + (size_t)(kt * 8 + nt)) * 1024;
    Wpk[base + l * 8 + r]       = hi;
    Wpk[base + 512 + l * 8 + r] = lo;
  }
}

// ---- projection GEMM on matrix cores (unchanged from R6 — control) ----
__global__ __launch_bounds__(256) void proj_mfma(
    const float* __restrict__ Xj, const float* __restrict__ Xi,
    const float* __restrict__ bias, const __half* __restrict__ Wpk,
    __half* __restrict__ Yj, __half* __restrict__ Yi, int nrows) {
  const int which = blockIdx.y;
  const float* X = which ? Xi : Xj;
  __half* Y = which ? Yi : Yj;
  const _Float16* WpkB = (const _Float16*)Wpk + (size_t)which * 32768;

  __shared__ _Float16 Wlds[2][8192];   // 2 x 16 KB kt-chunks

  const int tid  = threadIdx.x;
  const int wid  = tid >> 6;
  const int lane = tid & 63;
  const int lr   = lane & 15;
  const int lg   = lane >> 4;

  const long row0 = (long)blockIdx.x * 128 + wid * 32;
  long r0 = row0 + lr;
  long r1 = row0 + 16 + lr;
  const float* p0 = X + (r0 < nrows ? r0 : 0) * 128 + lg * 8;
  const float* p1 = X + (r1 < nrows ? r1 : 0) * 128 + lg * 8;

  // ---- prologue: stage W chunk 0 (16 KB = 1024 float4) + X for kt=0 ----
  {
    const float4* s_ = (const float4*)(WpkB);
    float4* d_ = (float4*)Wlds[0];
    d_[tid]       = s_[tid];
    d_[256 + tid] = s_[256 + tid];
    d_[512 + tid] = s_[512 + tid];
    d_[768 + tid] = s_[768 + tid];
  }
  float4 xa0 = *(const float4*)(p0);
  float4 xb0 = *(const float4*)(p0 + 4);
  float4 xa1 = *(const float4*)(p1);
  float4 xb1 = *(const float4*)(p1 + 4);

  __syncthreads();

  f32x4 acc[2][8] = {};

#define CVT1(dsth, dstl, idx, val)                                   \
  { float v_ = (val); _Float16 h_ = (_Float16)v_;                    \
    dsth[idx] = h_; dstl[idx] = (_Float16)(v_ - (float)h_); }
#define CVT8(dsth, dstl, v0, v1)                                     \
  CVT1(dsth, dstl, 0, (v0).x) CVT1(dsth, dstl, 1, (v0).y)            \
  CVT1(dsth, dstl, 2, (v0).z) CVT1(dsth, dstl, 3, (v0).w)            \
  CVT1(dsth, dstl, 4, (v1).x) CVT1(dsth, dstl, 5, (v1).y)            \
  CVT1(dsth, dstl, 6, (v1).z) CVT1(dsth, dstl, 7, (v1).w)

#define MFMA(a, b, c) __builtin_amdgcn_mfma_f32_16x16x32_f16((a), (b), (c), 0, 0, 0)

#define KT_STEP(kt, LAST)                                                \
  {                                                                      \
    float4 sw0, sw1, sw2, sw3;                                           \
    if (!(LAST)) {                                                       \
      const float4* s_ = (const float4*)(WpkB + ((kt) + 1) * 8192);      \
      sw0 = s_[tid];                                                     \
      sw1 = s_[256 + tid];                                               \
      sw2 = s_[512 + tid];                                               \
      sw3 = s_[768 + tid];                                               \
    }                                                                    \
    half8 xh0, xl0, xh1, xl1;                                            \
    CVT8(xh0, xl0, xa0, xb0);                                            \
    CVT8(xh1, xl1, xa1, xb1);                                            \
    if (!(LAST)) {                                                       \
      xa0 = *(const float4*)(p0 + ((kt) + 1) * 32);                      \
      xb0 = *(const float4*)(p0 + ((kt) + 1) * 32 + 4);                  \
      xa1 = *(const float4*)(p1 + ((kt) + 1) * 32);                      \
      xb1 = *(const float4*)(p1 + ((kt) + 1) * 32 + 4);                  \
      float4* d_ = (float4*)Wlds[((kt) + 1) & 1];                        \
      d_[tid]       = sw0;                                               \
      d_[256 + tid] = sw1;                                               \
      d_[512 + tid] = sw2;                                               \
      d_[768 + tid] = sw3;                                               \
    }                                                                    \
    _Pragma("unroll")                                                    \
    for (int nt = 0; nt < 8; ++nt) {                                     \
      const _Float16* f = &Wlds[(kt) & 1][nt * 1024 + lane * 8];         \
      half8 wh = *(const half8*)(f);                                     \
      half8 wl = *(const half8*)(f + 512);                               \
      acc[0][nt] = MFMA(wh, xh0, acc[0][nt]);                            \
      acc[1][nt] = MFMA(wh, xh1, acc[1][nt]);                            \
      acc[0][nt] = MFMA(wh, xl0, acc[0][nt]);                            \
      acc[1][nt] = MFMA(wh, xl1, acc[1][nt]);                            \
      acc[0][nt] = MFMA(wl, xh0, acc[0][nt]);                            \
      acc[1][nt] = MFMA(wl, xh1, acc[1][nt]);                            \
    }                                                                    \
    if (!(LAST)) __syncthreads();                                        \
  }

  KT_STEP(0, 0)
  KT_STEP(1, 0)
  KT_STEP(2, 0)
  KT_STEP(3, 1)

#undef KT_STEP
#undef MFMA
#undef CVT8
#undef CVT1

  // ---- epilogue: D layout (swapped): lane -> row = mt*16 + lr,
  //      cols = nt*16 + lg*4 + (0..3) -> packed 8B stores ----
  #pragma unroll
  for (int mt = 0; mt < 2; ++mt) {
    long row = row0 + mt * 16 + lr;
    if (row < nrows) {
      __half* yr = Y + row * 128;
      #pragma unroll
      for (int nt = 0; nt < 8; ++nt) {
        float4 bv = make_float4(0.f, 0.f, 0.f, 0.f);
        if (which) bv = *(const float4*)(bias + nt * 16 + lg * 4);
        __half2 v01 = __floats2half2_rn(acc[mt][nt][0] + bv.x, acc[mt][nt][1] + bv.y);
        __half2 v23 = __floats2half2_rn(acc[mt][nt][2] + bv.z, acc[mt][nt][3] + bv.w);
        uint2 u;
        u.x = *(unsigned int*)&v01;
        u.y = *(unsigned int*)&v23;
        *(uint2*)(yr + nt * 16 + lg * 4) = u;
      }
    }
  }
}

// One block per segment.
// v4 phase 1 (fix for VMEM-instruction-throughput wall: 28% VALU / 42% HBM /
// 71% occ with nothing saturated across 3 structures -> divergent-gather
// instruction issue is the limit, not bytes):
//  - per-edge index loads (8 broadcast instrs/iter) replaced by TWO aligned
//    int4 loads over consecutive edges -> 16 VMEM instrs/iter -> 10
//  - loop starts at start&~3 so int4 loads stay 16B-aligned; base clamped to
//    (E-4)&~3 for memory safety; alpha writes masked to [start,end)
//    (duplicate/wasted tail gathers are benign)
// Bytes per edge unchanged. Phases 2-4 unchanged.
__global__ __launch_bounds__(256) void seg_softmax(
    const __half* __restrict__ xjp, const __half* __restrict__ xip,
    const int* __restrict__ ei, const int* __restrict__ segs,
    const float* __restrict__ mlpW, const float* __restrict__ prelu_w,
    const float* __restrict__ mlp_b, float* __restrict__ out, int E) {
  const int start = segs[blockIdx.x];
  const int end = segs[blockIdx.x + 1];
  const int cnt = end - start;
  if (cnt <= 0) return;

  __shared__ float aS[CAP];
  __shared__ float red[8];

  const int tid = threadIdx.x;
  const int lane = tid & 63;
  const int wid = tid >> 6;
  const int g   = tid >> 4;          // 16 quarter-wave groups per block
  const int ql  = tid & 15;          // lane within group: 8 features x fp16

  const float4 w0 = *(const float4*)(mlpW + ql * 8);
  const float4 w1 = *(const float4*)(mlpW + ql * 8 + 4);
  const float pw = prelu_w[0];
  const float mb = mlp_b[0];
  const bool useLds = (cnt <= CAP);

  const uint4* XJ = (const uint4*)xjp;   // one row = 16 uint4 (256 B)
  const uint4* XI = (const uint4*)xip;
  const h2v pwv = { (_Float16)pw, (_Float16)pw };
  const h2v zv  = { (_Float16)0.f, (_Float16)0.f };

  const int ebMax = (E - 4) & ~3;        // last aligned, fully in-bounds base

  // ---- phase 1: alpha (4 consecutive edges per group per iteration) ----
  for (int e0 = (start & ~3) + g * 4; e0 < end; e0 += 64) {
    const int eb = e0 < ebMax ? e0 : ebMax;     // aligned + memory-safe
    const int4 sv = *(const int4*)(ei + eb);
    const int4 dv = *(const int4*)(ei + E + eb);

    uint4 aA = XJ[(size_t)sv.x * 16 + ql], bA = XI[(size_t)dv.x * 16 + ql];
    uint4 aB = XJ[(size_t)sv.y * 16 + ql], bB = XI[(size_t)dv.y * 16 + ql];
    uint4 aC = XJ[(size_t)sv.z * 16 + ql], bC = XI[(size_t)dv.z * 16 + ql];
    uint4 aD = XJ[(size_t)sv.w * 16 + ql], bD = XI[(size_t)dv.w * 16 + ql];

    float pA, pB, pC, pD;
#define EALPHA(av, bv, p)                                                   \
    {                                                                       \
      h2v h0 = *(h2v*)&(av).x + *(h2v*)&(bv).x;                             \
      h2v h1 = *(h2v*)&(av).y + *(h2v*)&(bv).y;                             \
      h2v h2 = *(h2v*)&(av).z + *(h2v*)&(bv).z;                             \
      h2v h3 = *(h2v*)&(av).w + *(h2v*)&(bv).w;                             \
      h0 = __builtin_elementwise_max(h0, zv)                                \
         + pwv * __builtin_elementwise_min(h0, zv);                         \
      h1 = __builtin_elementwise_max(h1, zv)                                \
         + pwv * __builtin_elementwise_min(h1, zv);                         \
      h2 = __builtin_elementwise_max(h2, zv)                                \
         + pwv * __builtin_elementwise_min(h2, zv);                         \
      h3 = __builtin_elementwise_max(h3, zv)                                \
         + pwv * __builtin_elementwise_min(h3, zv);                         \
      p = (float)h0.x * w0.x;                                               \
      p = fmaf((float)h0.y, w0.y, p); p = fmaf((float)h1.x, w0.z, p);       \
      p = fmaf((float)h1.y, w0.w, p); p = fmaf((float)h2.x, w1.x, p);       \
      p = fmaf((float)h2.y, w1.y, p); p = fmaf((float)h3.x, w1.z, p);       \
      p = fmaf((float)h3.y, w1.w, p);                                       \
    }
    EALPHA(aA, bA, pA);
    EALPHA(aB, bB, pB);
    EALPHA(aC, bC, pC);
    EALPHA(aD, bD, pD);
#undef EALPHA

    #pragma unroll
    for (int off = 1; off < 16; off <<= 1) {
      pA += __shfl_xor(pA, off, 64);
      pB += __shfl_xor(pB, off, 64);
      pC += __shfl_xor(pC, off, 64);
      pD += __shfl_xor(pD, off, 64);
    }
    if (ql == 0) {
      const int k0 = eb - start;   // may be negative (masked below)
      if (useLds) {
        if (k0 >= 0     && eb     < end) aS[k0]     = pA + mb;
        if (k0 + 1 >= 0 && eb + 1 < end) aS[k0 + 1] = pB + mb;
        if (k0 + 2 >= 0 && eb + 2 < end) aS[k0 + 2] = pC + mb;
        if (k0 + 3 >= 0 && eb + 3 < end) aS[k0 + 3] = pD + mb;
      } else {
        if (k0 >= 0     && eb     < end) out[eb]     = pA + mb;
        if (k0 + 1 >= 0 && eb + 1 < end) out[eb + 1] = pB + mb;
        if (k0 + 2 >= 0 && eb + 2 < end) out[eb + 2] = pC + mb;
        if (k0 + 3 >= 0 && eb + 3 < end) out[eb + 3] = pD + mb;
      }
    }
  }
  __syncthreads();

  // ---- phase 2: block max ----
  float m = -FLT_MAX;
  if (useLds) { for (int i = tid; i < cnt; i += 256) m = fmaxf(m, aS[i]); }
  else        { for (int i = tid; i < cnt; i += 256) m = fmaxf(m, out[start + i]); }
  #pragma unroll
  for (int off = 1; off < 64; off <<= 1) m = fmaxf(m, __shfl_xor(m, off, 64));
  if (lane == 0) red[wid] = m;
  __syncthreads();
  m = fmaxf(fmaxf(red[0], red[1]), fmaxf(red[2], red[3]));

  // ---- phase 3: exp + block sum ----
  float s = 0.f;
  if (useLds) {
    for (int i = tid; i < cnt; i += 256) { float x = expf(aS[i] - m); aS[i] = x; s += x; }
  } else {
    for (int i = tid; i < cnt; i += 256) { float x = expf(out[start + i] - m); out[start + i] = x; s += x; }
  }
  #pragma unroll
  for (int off = 1; off < 64; off <<= 1) s += __shfl_xor(s, off, 64);
  if (lane == 0) red[4 + wid] = s;
  __syncthreads();
  s = (red[4] + red[5]) + (red[6] + red[7]);

  // ---- phase 4: normalize + write ----
  const float inv = 1.0f / (s + 1e-16f);
  if (useLds) { for (int i = tid; i < cnt; i += 256) out[start + i] = aS[i] * inv; }
  else        { for (int i = tid; i < cnt; i += 256) out[start + i] *= inv; }
}

extern "C" void kernel_launch(void* const* d_in, const int* in_sizes, int n_in,
                              void* d_out, int out_size, void* d_ws, size_t ws_size,
                              hipStream_t stream) {
  const float* x_j      = (const float*)d_in[0];
  const float* x_i      = (const float*)d_in[1];
  const int*   edge_idx = (const int*)d_in[2];
  const int*   batch    = (const int*)d_in[3];
  const float* w_j      = (const float*)d_in[4];
  const float* w_i      = (const float*)d_in[5];
  const float* bias     = (const float*)d_in[6];
  const float* prelu_w  = (const float*)d_in[7];
  const float* mlp_W    = (const float*)d_in[8];
  const float* mlp_b    = (const float*)d_in[9];
  const int nnodes = in_sizes[0] / 128;
  const int E = in_sizes[3];

  __half* Wpk = (__half*)d_ws;                    // 65536 halves = 128 KB
  __half* xjp = Wpk + 65536;
  __half* xip = xjp + (size_t)nnodes * 128;
  int* segs   = (int*)(xip + (size_t)nnodes * 128);

  hipLaunchKernelGGL(seg_bounds, dim3((NSEG + 1 + 255) / 256), dim3(256), 0, stream,
                     batch, segs, E);

  hipLaunchKernelGGL(pack_w, dim3(32), dim3(256), 0, stream, w_j, w_i, Wpk);

  int gblocks = (nnodes + 127) / 128;
  hipLaunchKernelGGL(proj_mfma, dim3(gblocks, 2), dim3(256), 0, stream,
                     x_j, x_i, bias, Wpk, xjp, xip, nnodes);

  hipLaunchKernelGGL(seg_softmax, dim3(NSEG), dim3(256), 0, stream,
                     xjp, xip, edge_idx, segs, mlp_W, prelu_w, mlp_b,
                     (float*)d_out, E);
}

// Round 8
// 242.954 us; speedup vs baseline: 1.3250x; 1.0399x over previous
//
#include <hip/hip_runtime.h>
#include <hip/hip_fp16.h>
#include <float.h>

#define NSEG 4096
#define CAP 2048   // max edges/segment held in LDS (max segment count ~330)

typedef __attribute__((ext_vector_type(8))) _Float16 half8;
typedef __attribute__((ext_vector_type(2))) _Float16 h2v;
typedef __attribute__((ext_vector_type(4))) float f32x4;

// ---- fused setup: seg_bounds (blocks 0..16) + pack_w (blocks 17..48) ----
// Independent work items; fusing saves one kernel launch (~5-10 us of the
// fixed per-iteration overhead).
__global__ __launch_bounds__(256) void setup(
    const int* __restrict__ batch, int* __restrict__ segs, int E,
    const float* __restrict__ Wj, const float* __restrict__ Wi,
    __half* __restrict__ Wpk) {
  const int bid = blockIdx.x;
  if (bid < 17) {
    // segment boundaries: segs[b] = first edge index with batch >= b
    int b = bid * 256 + threadIdx.x;
    if (b > NSEG) return;
    int lo = 0, hi = E;
    while (lo < hi) { int mid = (lo + hi) >> 1; if (batch[mid] < b) lo = mid + 1; else hi = mid; }
    segs[b] = lo;
  } else {
    // pack W_j / W_i into MFMA fragment order, split fp16 hi/lo.
    // Layout (halves): Wpk[which][kt*8+nt][h(0=hi,1=lo)][lane][r]
    //   value = W[k][n], k = kt*32 + (l>>4)*8 + r, n = nt*16 + (l&15)
    // One kt-chunk = 8192 halves = 16 KB = 1024 float4, contiguous.
    int tid = (bid - 17) * 256 + threadIdx.x;
    for (int idx = tid; idx < 2 * 4 * 8 * 64 * 8; idx += 32 * 256) {
      int r     = idx & 7;
      int l     = (idx >> 3) & 63;
      int nt    = (idx >> 9) & 7;
      int kt    = (idx >> 12) & 3;
      int which = idx >> 14;
      const float* W = which ? Wi : Wj;
      int k = kt * 32 + (l >> 4) * 8 + r;
      int n = nt * 16 + (l & 15);
      float v = W[k * 128 + n];
      __half hi = __float2half(v);                         // RNE
      __half lo = __float2half(v - __half2float(hi));      // exact residual
      size_t base = ((size_t)which * 32 + (size_t)(kt * 8 + nt)) * 1024;
      Wpk[base + l * 8 + r]       = hi;
      Wpk[base + 512 + l * 8 + r] = lo;
    }
  }
}

// ---- projection GEMM on matrix cores: Y = fp16(X @ W (+bias for which==1)) ----
// v4 (occupancy + write-late schedule; numerics bitwise-identical to R6):
//  - 1 m-tile/wave (16 rows, acc=32 VGPR) -> ~100-110 VGPR total, under the
//    128 cliff -> 4 waves/SIMD; 32 KB LDS -> 4 blocks/CU = 16 waves/CU
//  - T14 write-late W staging: issue next-chunk global loads FIRST, run the
//    MFMA cluster, THEN ds_write+barrier -> the vmcnt wait sits behind the
//    MFMAs instead of in front of them
//  - X prefetch depth 2 (covers ~2 steps of HBM latency)
__global__ __launch_bounds__(256) void proj_mfma(
    const float* __restrict__ Xj, const float* __restrict__ Xi,
    const float* __restrict__ bias, const __half* __restrict__ Wpk,
    __half* __restrict__ Yj, __half* __restrict__ Yi, int nrows) {
  const int which = blockIdx.y;
  const float* X = which ? Xi : Xj;
  __half* Y = which ? Yi : Yj;
  const _Float16* WpkB = (const _Float16*)Wpk + (size_t)which * 32768;

  __shared__ _Float16 Wlds[2][8192];   // 2 x 16 KB kt-chunks

  const int tid  = threadIdx.x;
  const int wid  = tid >> 6;
  const int lane = tid & 63;
  const int lr   = lane & 15;   // X row within the wave's 16-row tile
  const int lg   = lane >> 4;   // k-chunk group; D reg-quad selects output cols

  const long row0 = (long)blockIdx.x * 64 + wid * 16;   // wave's 16 rows
  long r0 = row0 + lr;
  const float* p0 = X + (r0 < nrows ? r0 : 0) * 128 + lg * 8;  // clamp: safe read

  // ---- prologue: stage W chunk 0 (16 KB = 1024 float4); X for kt=0,1 ----
  {
    const float4* s_ = (const float4*)(WpkB);
    float4* d_ = (float4*)Wlds[0];
    d_[tid]       = s_[tid];
    d_[256 + tid] = s_[256 + tid];
    d_[512 + tid] = s_[512 + tid];
    d_[768 + tid] = s_[768 + tid];
  }
  float4 xa = *(const float4*)(p0);
  float4 xb = *(const float4*)(p0 + 4);
  float4 na = *(const float4*)(p0 + 32);
  float4 nb = *(const float4*)(p0 + 36);

  __syncthreads();

  f32x4 acc[8] = {};

#define CVT1(dsth, dstl, idx, val)                                   \
  { float v_ = (val); _Float16 h_ = (_Float16)v_;                    \
    dsth[idx] = h_; dstl[idx] = (_Float16)(v_ - (float)h_); }
#define CVT8(dsth, dstl, v0, v1)                                     \
  CVT1(dsth, dstl, 0, (v0).x) CVT1(dsth, dstl, 1, (v0).y)            \
  CVT1(dsth, dstl, 2, (v0).z) CVT1(dsth, dstl, 3, (v0).w)            \
  CVT1(dsth, dstl, 4, (v1).x) CVT1(dsth, dstl, 5, (v1).y)            \
  CVT1(dsth, dstl, 6, (v1).z) CVT1(dsth, dstl, 7, (v1).w)

#define MFMA(a, b, c) __builtin_amdgcn_mfma_f32_16x16x32_f16((a), (b), (c), 0, 0, 0)

// HASN1: chunk kt+1 exists (stage W, shift X); HASN2: kt+2 exists (load X)
#define KT_STEP(kt, HASN1, HASN2)                                        \
  {                                                                      \
    float4 sw0, sw1, sw2, sw3;                                           \
    if (HASN1) {                                                         \
      const float4* s_ = (const float4*)(WpkB + ((kt) + 1) * 8192);      \
      sw0 = s_[tid];                                                     \
      sw1 = s_[256 + tid];                                               \
      sw2 = s_[512 + tid];                                               \
      sw3 = s_[768 + tid];                                               \
    }                                                                    \
    half8 xh, xl;                                                        \
    CVT8(xh, xl, xa, xb);                                                \
    if (HASN1) { xa = na; xb = nb; }                                     \
    if (HASN2) {                                                         \
      na = *(const float4*)(p0 + ((kt) + 2) * 32);                       \
      nb = *(const float4*)(p0 + ((kt) + 2) * 32 + 4);                   \
    }                                                                    \
    _Pragma("unroll")                                                    \
    for (int nt = 0; nt < 8; ++nt) {                                     \
      const _Float16* f = &Wlds[(kt) & 1][nt * 1024 + lane * 8];         \
      half8 wh = *(const half8*)(f);                                     \
      half8 wl = *(const half8*)(f + 512);                               \
      acc[nt] = MFMA(wh, xh, acc[nt]);                                   \
      acc[nt] = MFMA(wh, xl, acc[nt]);                                   \
      acc[nt] = MFMA(wl, xh, acc[nt]);                                   \
    }                                                                    \
    if (HASN1) {                                                         \
      float4* d_ = (float4*)Wlds[((kt) + 1) & 1];                        \
      d_[tid]       = sw0;                                               \
      d_[256 + tid] = sw1;                                               \
      d_[512 + tid] = sw2;                                               \
      d_[768 + tid] = sw3;                                               \
      __syncthreads();                                                   \
    }                                                                    \
  }

  KT_STEP(0, 1, 1)
  KT_STEP(1, 1, 1)
  KT_STEP(2, 1, 0)
  KT_STEP(3, 0, 0)

#undef KT_STEP
#undef MFMA
#undef CVT8
#undef CVT1

  // ---- epilogue: D layout (swapped operands): lane -> row = row0 + lr,
  //      cols = nt*16 + lg*4 + (0..3) -> packed 8B stores ----
  long row = row0 + lr;
  if (row < nrows) {
    __half* yr = Y + row * 128;
    #pragma unroll
    for (int nt = 0; nt < 8; ++nt) {
      float4 bv = make_float4(0.f, 0.f, 0.f, 0.f);
      if (which) bv = *(const float4*)(bias + nt * 16 + lg * 4);
      __half2 v01 = __floats2half2_rn(acc[nt][0] + bv.x, acc[nt][1] + bv.y);
      __half2 v23 = __floats2half2_rn(acc[nt][2] + bv.z, acc[nt][3] + bv.w);
      uint2 u;
      u.x = *(unsigned int*)&v01;
      u.y = *(unsigned int*)&v23;
      *(uint2*)(yr + nt * 16 + lg * 4) = u;
    }
  }
}

// One block per segment. (FROZEN since R7 — at a pattern-BW wall: 72-76 us /
// 3.3-3.4 TB/s beyond-L2 invariant across 4 structures; traffic irreducible
// in fp16 and fp8 fails the error budget)
__global__ __launch_bounds__(256) void seg_softmax(
    const __half* __restrict__ xjp, const __half* __restrict__ xip,
    const int* __restrict__ ei, const int* __restrict__ segs,
    const float* __restrict__ mlpW, const float* __restrict__ prelu_w,
    const float* __restrict__ mlp_b, float* __restrict__ out, int E) {
  const int start = segs[blockIdx.x];
  const int end = segs[blockIdx.x + 1];
  const int cnt = end - start;
  if (cnt <= 0) return;

  __shared__ float aS[CAP];
  __shared__ float red[8];

  const int tid = threadIdx.x;
  const int lane = tid & 63;
  const int wid = tid >> 6;
  const int g   = tid >> 4;          // 16 quarter-wave groups per block
  const int ql  = tid & 15;          // lane within group: 8 features x fp16

  const float4 w0 = *(const float4*)(mlpW + ql * 8);
  const float4 w1 = *(const float4*)(mlpW + ql * 8 + 4);
  const float pw = prelu_w[0];
  const float mb = mlp_b[0];
  const bool useLds = (cnt <= CAP);

  const uint4* XJ = (const uint4*)xjp;   // one row = 16 uint4 (256 B)
  const uint4* XI = (const uint4*)xip;
  const h2v pwv = { (_Float16)pw, (_Float16)pw };
  const h2v zv  = { (_Float16)0.f, (_Float16)0.f };

  // ---- phase 1: alpha (4 consecutive edges per group per iteration) ----
  for (int e0 = start + g * 4; e0 < end; e0 += 64) {
    const int eB = e0 + 1, eC = e0 + 2, eD = e0 + 3;
    const bool vB = (eB < end), vC = (eC < end), vD = (eD < end);
    int sA = ei[e0],            dA = ei[E + e0];
    int sB = vB ? ei[eB] : sA,  dB = vB ? ei[E + eB] : dA;
    int sC = vC ? ei[eC] : sA,  dC = vC ? ei[E + eC] : dA;
    int sD = vD ? ei[eD] : sA,  dD = vD ? ei[E + eD] : dA;

    uint4 aA = XJ[(size_t)sA * 16 + ql], bA = XI[(size_t)dA * 16 + ql];
    uint4 aB = XJ[(size_t)sB * 16 + ql], bB = XI[(size_t)dB * 16 + ql];
    uint4 aC = XJ[(size_t)sC * 16 + ql], bC = XI[(size_t)dC * 16 + ql];
    uint4 aD = XJ[(size_t)sD * 16 + ql], bD = XI[(size_t)dD * 16 + ql];

    float pA, pB, pC, pD;
#define EALPHA(av, bv, p)                                                   \
    {                                                                       \
      h2v h0 = *(h2v*)&(av).x + *(h2v*)&(bv).x;                             \
      h2v h1 = *(h2v*)&(av).y + *(h2v*)&(bv).y;                             \
      h2v h2 = *(h2v*)&(av).z + *(h2v*)&(bv).z;                             \
      h2v h3 = *(h2v*)&(av).w + *(h2v*)&(bv).w;                             \
      h0 = __builtin_elementwise_max(h0, zv)                                \
         + pwv * __builtin_elementwise_min(h0, zv);                         \
      h1 = __builtin_elementwise_max(h1, zv)                                \
         + pwv * __builtin_elementwise_min(h1, zv);                         \
      h2 = __builtin_elementwise_max(h2, zv)                                \
         + pwv * __builtin_elementwise_min(h2, zv);                         \
      h3 = __builtin_elementwise_max(h3, zv)                                \
         + pwv * __builtin_elementwise_min(h3, zv);                         \
      p = (float)h0.x * w0.x;                                               \
      p = fmaf((float)h0.y, w0.y, p); p = fmaf((float)h1.x, w0.z, p);       \
      p = fmaf((float)h1.y, w0.w, p); p = fmaf((float)h2.x, w1.x, p);       \
      p = fmaf((float)h2.y, w1.y, p); p = fmaf((float)h3.x, w1.z, p);       \
      p = fmaf((float)h3.y, w1.w, p);                                       \
    }
    EALPHA(aA, bA, pA);
    EALPHA(aB, bB, pB);
    EALPHA(aC, bC, pC);
    EALPHA(aD, bD, pD);
#undef EALPHA

    #pragma unroll
    for (int off = 1; off < 16; off <<= 1) {
      pA += __shfl_xor(pA, off, 64);
      pB += __shfl_xor(pB, off, 64);
      pC += __shfl_xor(pC, off, 64);
      pD += __shfl_xor(pD, off, 64);
    }
    if (ql == 0) {
      if (useLds) {
        aS[e0 - start] = pA + mb;
        if (vB) aS[eB - start] = pB + mb;
        if (vC) aS[eC - start] = pC + mb;
        if (vD) aS[eD - start] = pD + mb;
      } else {
        out[e0] = pA + mb;
        if (vB) out[eB] = pB + mb;
        if (vC) out[eC] = pC + mb;
        if (vD) out[eD] = pD + mb;
      }
    }
  }
  __syncthreads();

  // ---- phase 2: block max ----
  float m = -FLT_MAX;
  if (useLds) { for (int i = tid; i < cnt; i += 256) m = fmaxf(m, aS[i]); }
  else        { for (int i = tid; i < cnt; i += 256) m = fmaxf(m, out[start + i]); }
  #pragma unroll
  for (int off = 1; off < 64; off <<= 1) m = fmaxf(m, __shfl_xor(m, off, 64));
  if (lane == 0) red[wid] = m;
  __syncthreads();
  m = fmaxf(fmaxf(red[0], red[1]), fmaxf(red[2], red[3]));

  // ---- phase 3: exp + block sum ----
  float s = 0.f;
  if (useLds) {
    for (int i = tid; i < cnt; i += 256) { float x = expf(aS[i] - m); aS[i] = x; s += x; }
  } else {
    for (int i = tid; i < cnt; i += 256) { float x = expf(out[start + i] - m); out[start + i] = x; s += x; }
  }
  #pragma unroll
  for (int off = 1; off < 64; off <<= 1) s += __shfl_xor(s, off, 64);
  if (lane == 0) red[4 + wid] = s;
  __syncthreads();
  s = (red[4] + red[5]) + (red[6] + red[7]);

  // ---- phase 4: normalize + write ----
  const float inv = 1.0f / (s + 1e-16f);
  if (useLds) { for (int i = tid; i < cnt; i += 256) out[start + i] = aS[i] * inv; }
  else        { for (int i = tid; i < cnt; i += 256) out[start + i] *= inv; }
}

extern "C" void kernel_launch(void* const* d_in, const int* in_sizes, int n_in,
                              void* d_out, int out_size, void* d_ws, size_t ws_size,
                              hipStream_t stream) {
  const float* x_j      = (const float*)d_in[0];
  const float* x_i      = (const float*)d_in[1];
  const int*   edge_idx = (const int*)d_in[2];
  const int*   batch    = (const int*)d_in[3];
  const float* w_j      = (const float*)d_in[4];
  const float* w_i      = (const float*)d_in[5];
  const float* bias     = (const float*)d_in[6];
  const float* prelu_w  = (const float*)d_in[7];
  const float* mlp_W    = (const float*)d_in[8];
  const float* mlp_b    = (const float*)d_in[9];
  const int nnodes = in_sizes[0] / 128;
  const int E = in_sizes[3];

  __half* Wpk = (__half*)d_ws;                    // 65536 halves = 128 KB
  __half* xjp = Wpk + 65536;
  __half* xip = xjp + (size_t)nnodes * 128;
  int* segs   = (int*)(xip + (size_t)nnodes * 128);

  hipLaunchKernelGGL(setup, dim3(49), dim3(256), 0, stream,
                     batch, segs, E, w_j, w_i, Wpk);

  int gblocks = (nnodes + 63) / 64;
  hipLaunchKernelGGL(proj_mfma, dim3(gblocks, 2), dim3(256), 0, stream,
                     x_j, x_i, bias, Wpk, xjp, xip, nnodes);

  hipLaunchKernelGGL(seg_softmax, dim3(NSEG), dim3(256), 0, stream,
                     xjp, xip, edge_idx, segs, mlp_W, prelu_w, mlp_b,
                     (float*)d_out, E);
}